// Round 14
// baseline (117.188 us; speedup 1.0000x reference)
//
#include <hip/hip_runtime.h>
#include <stdint.h>
#include <math.h>

#define DEVFN __device__ __forceinline__
typedef unsigned short u16;
typedef short bf16x8 __attribute__((ext_vector_type(8)));
typedef float f32x4  __attribute__((ext_vector_type(4)));

// ---------------------------------------------------------------- helpers
DEVFN float blk_sum(float v, float* s4) {          // 256-thread block sum
  #pragma unroll
  for (int o = 32; o > 0; o >>= 1) v += __shfl_down(v, o, 64);
  __syncthreads();
  if ((threadIdx.x & 63) == 0) s4[threadIdx.x >> 6] = v;
  __syncthreads();
  return s4[0] + s4[1] + s4[2] + s4[3];
}

// fused 3-value block sum (one barrier pair instead of three)
DEVFN void blk_sum3(float a, float b, float c, float* out, float (*s)[4]) {
  #pragma unroll
  for (int o = 32; o > 0; o >>= 1) {
    a += __shfl_down(a, o, 64);
    b += __shfl_down(b, o, 64);
    c += __shfl_down(c, o, 64);
  }
  __syncthreads();
  if ((threadIdx.x & 63) == 0) {
    int wi = threadIdx.x >> 6;
    s[0][wi] = a; s[1][wi] = b; s[2][wi] = c;
  }
  __syncthreads();
  out[0] = s[0][0] + s[0][1] + s[0][2] + s[0][3];
  out[1] = s[1][0] + s[1][1] + s[1][2] + s[1][3];
  out[2] = s[2][0] + s[2][1] + s[2][2] + s[2][3];
}

DEVFN void blk_sum2(float a, float b, float* out, float (*s)[4]) {
  #pragma unroll
  for (int o = 32; o > 0; o >>= 1) {
    a += __shfl_down(a, o, 64);
    b += __shfl_down(b, o, 64);
  }
  __syncthreads();
  if ((threadIdx.x & 63) == 0) {
    int wi = threadIdx.x >> 6;
    s[0][wi] = a; s[1][wi] = b;
  }
  __syncthreads();
  out[0] = s[0][0] + s[0][1] + s[0][2] + s[0][3];
  out[1] = s[1][0] + s[1][1] + s[1][2] + s[1][3];
}

DEVFN float gelu_f(float x) {
  return 0.5f * x * (1.f + erff(x * 0.7071067811865475f));
}

DEVFN u16 bf16_rne(float f) {                      // fp32 -> bf16 round-nearest-even
  uint32_t u = __float_as_uint(f);
  return (u16)((u + 0x7fffu + ((u >> 16) & 1u)) >> 16);
}

DEVFN float bf2f(u16 v) { return __uint_as_float(((uint32_t)v) << 16); }

// async global->LDS, 16B/lane; LDS dest = wave-uniform base + lane*16.
DEVFN void gload16(const u16* g, u16* l) {
  auto gp = (const __attribute__((address_space(1))) uint32_t*)(uintptr_t)g;
  auto lp = (__attribute__((address_space(3))) uint32_t*)(uintptr_t)l;
  __builtin_amdgcn_global_load_lds(gp, lp, 16, 0, 0);
}

// legacy helpers (L4/L7): row-major [64][256] with XOR source-side swizzle
DEVFN void stage64x256(const u16* G, size_t gstride, u16* L, int w, int lane) {
  #pragma unroll
  for (int i = 0; i < 8; ++i) {
    int row = w * 16 + 2 * i + (lane >> 5);
    int c16 = (lane & 31) ^ (row & 7);
    gload16(G + (size_t)row * gstride + c16 * 8, L + (w * 16 + 2 * i) * 256);
  }
}
DEVFN bf16x8 lread(const u16* L, int row, int k16) {
  return *(const bf16x8*)&L[row * 256 + ((k16 ^ (row & 7)) << 3)];
}

// ---------------------------------------------------------------- L1: local tok + weight prep rider
DEVFN void trc_tile(const float* __restrict__ in, u16* __restrict__ out,
                    int R, int C, int r0, int c0, float (*tile)[33], int tid) {
  int tx = tid & 31, ty = tid >> 5;
  for (int i = ty; i < 32; i += 8) tile[i][tx] = in[(size_t)(r0 + i) * C + c0 + tx];
  __syncthreads();
  for (int i = ty; i < 32; i += 8)
    out[(size_t)(c0 + i) * R + r0 + tx] = bf16_rne(tile[tx][i]);
}

__global__ __launch_bounds__(256) void k_l_tok_prep(
    const float* __restrict__ x, const float* __restrict__ pw,
    const float* __restrict__ pb, const float* __restrict__ g1,
    const float* __restrict__ b1, float* __restrict__ res,
    u16* __restrict__ eln_bf, float* __restrict__ g_part,
    const float* __restrict__ wq, const float* __restrict__ wk,
    const float* __restrict__ wv, const float* __restrict__ wo,
    const float* __restrict__ mow, u16* __restrict__ WcatT,
    u16* __restrict__ woT, u16* __restrict__ moB) {
  __shared__ __align__(16) char smem[8448];
  int bid0 = blockIdx.x, tid = threadIdx.x;
  if (bid0 < 1728) {
    float* pws = (float*)smem;
    float (*s3)[4] = (float(*)[4])(smem + 256);
    int t = bid0;
    int b = t / 216, s = t % 216;
    int z = s / 36, y = (s / 6) % 6, xx = s % 6;
    int d = z >> 1, p1 = z & 1, hh = y >> 1, p2 = y & 1, ww = xx >> 1, p3 = xx & 1;
    int p = p1 * 4 + p2 * 2 + p3;
    int c = tid;
    if (c < 64) pws[c] = pw[c];
    __syncthreads();
    const float* xb = x + (b * 256 + c) * 216 + (2 * d) * 36 + (2 * hh) * 6 + 2 * ww;
    float v = pb[p];
    float xs = 0.f;
    #pragma unroll
    for (int q1 = 0; q1 < 2; ++q1)
      #pragma unroll
      for (int q2 = 0; q2 < 2; ++q2)
        #pragma unroll
        for (int q3 = 0; q3 < 2; ++q3) {
          float xv = xb[q1 * 36 + q2 * 6 + q3];
          xs += xv;
          v += xv * pws[p * 8 + (q1 * 4 + q2 * 2 + q3)];
        }
    float r3[3];
    blk_sum3(xs, v, v * v, r3, s3);
    if (c == 0) g_part[t] = r3[0];
    res[t * 256 + c] = v;
    float mu = r3[1] * (1.f / 256.f);
    float var = r3[2] * (1.f / 256.f) - mu * mu;
    eln_bf[t * 256 + c] = bf16_rne((v - mu) * rsqrtf(var + 1e-6f) * g1[c] + b1[c]);
  } else {
    float (*tile)[33] = (float(*)[33])smem;
    int bid = bid0 - 1728;
    if (bid < 768) {            // wq/wk/wv: [256][1024] -> [1024][256]
      int which = bid >> 8, b2 = bid & 255;
      const float* in = (which == 0) ? wq : (which == 1) ? wk : wv;
      u16* out = WcatT + which * 262144;
      int r0 = (b2 & 7) * 32, c0 = (b2 >> 3) * 32;
      trc_tile(in, out, 256, 1024, r0, c0, tile, tid);
    } else if (bid < 1024) {    // wo: [1024][256] -> [256][1024]
      int b2 = bid - 768;
      int r0 = (b2 & 31) * 32, c0 = (b2 >> 5) * 32;
      trc_tile(wo, woT, 1024, 256, r0, c0, tile, tid);
    } else {                    // mo_w cast
      int i = (bid - 1024) * 256 + tid;
      moB[i] = bf16_rne(mow[i]);
    }
  }
}

// ---------------------------------------------------------------- L2a: local qkv GEMM (standalone)
// M=1728,N=3072,K=256; 64x64 tile; full-K single-drain preload into
// CHUNK-MAJOR LDS [32 k-chunks][64 rows][16B] (bank-clean per r12 measurement;
// uniform-chunk gather: per-instruction lanes stride by K rows only).
// XCD-chunked bijective swizzle (1296 = 8*162): each XCD's L2 owns a B-slice.
// bf16 output staged via padded LDS tile -> full-line uint4 stores.
__global__ __launch_bounds__(256) void k_gemm_qkv(
    const u16* __restrict__ A, const u16* __restrict__ BT, u16* __restrict__ C) {
  __shared__ __align__(16) u16 aL[16384];   // 32KB
  __shared__ __align__(16) u16 bL[16384];   // 32KB
  const int N = 3072, K = 256;
  int bid = blockIdx.x;
  int tile = (bid & 7) * 162 + (bid >> 3);
  int rowblk = (tile % 27) * 64, colblk = (tile / 27) * 64;
  int tid = threadIdx.x, lane = tid & 63, w = tid >> 6;
  int wr = (w >> 1) * 32, wc = (w & 1) * 32;
  int fm = lane & 15, lg = lane >> 4;
  #pragma unroll
  for (int i = 0; i < 8; ++i) {
    int c16 = w * 8 + i;                     // uniform chunk per instruction
    gload16(&A[(size_t)(rowblk + lane) * K + c16 * 8], aL + c16 * 512);
    gload16(&BT[(size_t)(colblk + lane) * K + c16 * 8], bL + c16 * 512);
  }
  __syncthreads();                           // single drain of all 16 loads
  f32x4 acc[2][2] = {};
  #pragma unroll
  for (int kk = 0; kk < 8; ++kk) {
    int k16 = kk * 4 + lg;
    bf16x8 bn0 = *(const bf16x8*)&bL[k16 * 512 + (wc + fm) * 8];
    bf16x8 bn1 = *(const bf16x8*)&bL[k16 * 512 + (wc + 16 + fm) * 8];
    bf16x8 af0 = *(const bf16x8*)&aL[k16 * 512 + (wr + fm) * 8];
    bf16x8 af1 = *(const bf16x8*)&aL[k16 * 512 + (wr + 16 + fm) * 8];
    acc[0][0] = __builtin_amdgcn_mfma_f32_16x16x32_bf16(af0, bn0, acc[0][0], 0, 0, 0);
    acc[0][1] = __builtin_amdgcn_mfma_f32_16x16x32_bf16(af0, bn1, acc[0][1], 0, 0, 0);
    acc[1][0] = __builtin_amdgcn_mfma_f32_16x16x32_bf16(af1, bn0, acc[1][0], 0, 0, 0);
    acc[1][1] = __builtin_amdgcn_mfma_f32_16x16x32_bf16(af1, bn1, acc[1][1], 0, 0, 0);
  }
  __syncthreads();                           // LDS safe to repurpose
  u16* ct = aL;                              // [64][72] bf16 (padded rows)
  #pragma unroll
  for (int mi = 0; mi < 2; ++mi)
    #pragma unroll
    for (int ni = 0; ni < 2; ++ni)
      #pragma unroll
      for (int r = 0; r < 4; ++r)
        ct[(wr + mi * 16 + lg * 4 + r) * 72 + wc + ni * 16 + fm] = bf16_rne(acc[mi][ni][r]);
  __syncthreads();
  #pragma unroll
  for (int pass = 0; pass < 2; ++pass) {
    int id = pass * 256 + tid;
    int r = id >> 3, u = id & 7;
    *(uint4*)&C[(size_t)(rowblk + r) * N + colblk + u * 8] = *(uint4*)&ct[r * 72 + u * 8];
  }
}

// ---------------------------------------------------------------- L2b: global tok+LN1+qkv (rider, standalone)
__global__ __launch_bounds__(256) void k_g_qkv(
    const float* __restrict__ g_part, const float* __restrict__ tw_,
    const float* __restrict__ tb_, const float* __restrict__ g1,
    const float* __restrict__ b1, const float* __restrict__ wq,
    const float* __restrict__ wk, const float* __restrict__ wv,
    float* __restrict__ gqkv) {
  __shared__ float ts[2048];
  __shared__ float red[64][4][8];
  __shared__ float s4[4], m_s[8];
  int tid = threadIdx.x;
  float tw = tw_[tid], tb = tb_[tid], gg = g1[tid], bb = b1[tid];
  float S1 = blk_sum(tw, s4);
  float S2 = blk_sum(tw * tw, s4);
  float S3 = blk_sum(tb, s4);
  float S4 = blk_sum(tb * tb, s4);
  float S5 = blk_sum(tw * tb, s4);
  {
    int b = tid >> 5, sl = tid & 31;
    float a = 0.f;
    for (int k = sl; k < 216; k += 32) a += g_part[b * 216 + k];
    #pragma unroll
    for (int o = 16; o > 0; o >>= 1) a += __shfl_down(a, o, 32);
    if (sl == 0) m_s[b] = a * (1.f / 442368.f);   // 8 * 55296 over-count
  }
  __syncthreads();
  #pragma unroll
  for (int b = 0; b < 8; ++b) {
    float m = m_s[b];
    float mu = (m * S1 + S3) * (1.f / 256.f);
    float var = (m * m * S2 + 2.f * m * S5 + S4) * (1.f / 256.f) - mu * mu;
    ts[b * 256 + tid] = (m * tw + tb - mu) * rsqrtf(var + 1e-6f) * gg + bb;
  }
  __syncthreads();
  int col0 = blockIdx.x * 64;
  int cl = tid & 63, kq = tid >> 6;
  int col = col0 + cl;
  int m = col >> 10, cc = col & 1023;
  const float* W = (m == 0) ? wq : (m == 1) ? wk : wv;
  float acc[8] = {};
  for (int c = kq * 64; c < kq * 64 + 64; ++c) {
    float w = W[c * 1024 + cc];
    #pragma unroll
    for (int b = 0; b < 8; ++b) acc[b] = fmaf(ts[b * 256 + c], w, acc[b]);
  }
  #pragma unroll
  for (int b = 0; b < 8; ++b) red[cl][kq][b] = acc[b];
  __syncthreads();
  if (kq == 0) {
    #pragma unroll
    for (int b = 0; b < 8; ++b)
      gqkv[b * 3072 + col] = red[cl][0][b] + red[cl][1][b] + red[cl][2][b] + red[cl][3][b];
  }
}

// ---------------------------------------------------------------- L3: local attention + global attn rider
__global__ __launch_bounds__(256) void k_l_attn_fused(
    const u16* __restrict__ qkv, u16* __restrict__ o_buf,
    const float* __restrict__ gq, float* __restrict__ g_o) {
  __shared__ __align__(16) uint4 Qb[256], Kb[256];
  __shared__ __align__(16) u16 vt[16][264];
  __shared__ __align__(16) u16 Pl[256][72];
  __shared__ float rqA[64][4], rkA[64][4], rlq[64][4], rlk[64][4], s_ab[2];
  int bid = blockIdx.x, tid = threadIdx.x;
  if (bid >= 864) {                       // ---- global attn rider
    float* ks = (float*)Qb;               // overlay: 1KB
    float* vs = ks + 256;
    float* s4 = (float*)Kb;
    int idx = bid - 864;
    int b = idx >> 2, h = idx & 3;
    int i = tid;
    const float* base = gq + b * 3072 + h * 256;
    float q = base[i];
    float k = base[1024 + i];
    ks[i] = k;
    vs[i] = base[2048 + i];
    float sq  = blk_sum(q, s4);
    float sq2 = blk_sum(q * q, s4);
    float sk  = blk_sum(k, s4);
    float sk2 = blk_sum(k * k, s4);
    float tot  = sq * sk * (1.f / 65536.f);
    float tot2 = sq2 * sk2 * (1.f / 65536.f);
    float rstd = rsqrtf(tot2 - tot * tot + 1e-5f);
    float A = rstd, B = -tot * rstd;
    float den = 0.f, num = 0.f;
    for (int j = 0; j < 256; ++j) {
      float w = __expf(fmaf(q * ks[j], A, B));
      den += w; num += w * vs[j];
    }
    g_o[b * 1024 + (i << 2) + h] = num / den;
    return;
  }
  int n = bid >> 2, h = bid & 3;
  int b = n / 27, patch = n % 27;
  int bz = 2 * (patch / 9), by = 2 * ((patch / 3) % 3), bx = 2 * (patch % 3);
  {
    int c = tid;
    u16 qv[8], kv[8], vv[8];
    #pragma unroll
    for (int p = 0; p < 8; ++p) {
      int t_l = b * 216 + (bz + (p >> 2)) * 36 + (by + ((p >> 1) & 1)) * 6 + (bx + (p & 1));
      const u16* row = qkv + (size_t)t_l * 3072 + (c << 2) + h;
      qv[p] = row[0]; kv[p] = row[1024]; vv[p] = row[2048];
    }
    uint32_t qw[4], kw[4];
    #pragma unroll
    for (int i = 0; i < 4; ++i) {
      qw[i] = (uint32_t)qv[2 * i] | ((uint32_t)qv[2 * i + 1] << 16);
      kw[i] = (uint32_t)kv[2 * i] | ((uint32_t)kv[2 * i + 1] << 16);
    }
    Qb[c] = make_uint4(qw[0], qw[1], qw[2], qw[3]);
    Kb[c] = make_uint4(kw[0], kw[1], kw[2], kw[3]);
    #pragma unroll
    for (int p = 0; p < 8; ++p) vt[p][c] = vv[p];
    vt[8][c] = 0x3F80u;                  // bf16(1.0): denominator ones-row
    #pragma unroll
    for (int r2 = 9; r2 < 16; ++r2) vt[r2][c] = 0;
  }
  __syncthreads();
  {
    int p = tid & 63, chunk = tid >> 6;
    int d = p >> 3, e = p & 7;
    float aq = 0.f, ak = 0.f, lq = 0.f, lk = 0.f;
    for (int cc = chunk * 64; cc < chunk * 64 + 64; ++cc) {
      const u16* qr = (const u16*)&Qb[cc];
      const u16* kr = (const u16*)&Kb[cc];
      float qd = bf2f(qr[d]), qe = bf2f(qr[e]);
      float kd = bf2f(kr[d]), ke = bf2f(kr[e]);
      aq = fmaf(qd, qe, aq); ak = fmaf(kd, ke, ak);
      if (e == 0) { lq += qd; lk += kd; }
    }
    rqA[p][chunk] = aq; rkA[p][chunk] = ak; rlq[p][chunk] = lq; rlk[p][chunk] = lk;
    __syncthreads();
    if (tid < 64) {
      float gq2 = rqA[tid][0] + rqA[tid][1] + rqA[tid][2] + rqA[tid][3];
      float gk = rkA[tid][0] + rkA[tid][1] + rkA[tid][2] + rkA[tid][3];
      float vprod = gq2 * gk, vmu = 0.f;
      if ((tid & 7) == 0) {
        float slq = rlq[tid][0] + rlq[tid][1] + rlq[tid][2] + rlq[tid][3];
        float slk = rlk[tid][0] + rlk[tid][1] + rlk[tid][2] + rlk[tid][3];
        vmu = slq * slk;
      }
      #pragma unroll
      for (int o = 32; o > 0; o >>= 1) {
        vprod += __shfl_down(vprod, o, 64);
        vmu   += __shfl_down(vmu, o, 64);
      }
      if (tid == 0) {
        float mu = vmu * (1.f / 65536.f), m2 = vprod * (1.f / 65536.f);
        float rstd = rsqrtf(m2 - mu * mu + 1e-5f);
        s_ab[0] = rstd; s_ab[1] = -mu * rstd;
      }
    }
    __syncthreads();
  }
  float Af = s_ab[0], Bf = s_ab[1];
  int lane = tid & 63, w = tid >> 6;
  int l15 = lane & 15, lg = lane >> 4;
  bf16x8 qf[4];
  #pragma unroll
  for (int qt = 0; qt < 4; ++qt)
    qf[qt] = *(const bf16x8*)&Qb[w * 64 + qt * 16 + l15];
  f32x4 acc_o[4] = {};
  #pragma unroll 1
  for (int jc = 0; jc < 4; ++jc) {
    bf16x8 kf[4];
    #pragma unroll
    for (int jt = 0; jt < 4; ++jt) {
      bf16x8 z = {};
      if (lg == 0) z = *(const bf16x8*)&Kb[jc * 64 + jt * 16 + l15];
      kf[jt] = z;
    }
    #pragma unroll
    for (int jt = 0; jt < 4; ++jt) {
      #pragma unroll
      for (int qt = 0; qt < 4; ++qt) {
        f32x4 zc = {};
        f32x4 s = __builtin_amdgcn_mfma_f32_16x16x32_bf16(kf[jt], qf[qt], zc, 0, 0, 0);
        float e0 = __expf(fmaf(s[0], Af, Bf));
        float e1 = __expf(fmaf(s[1], Af, Bf));
        float e2 = __expf(fmaf(s[2], Af, Bf));
        float e3 = __expf(fmaf(s[3], Af, Bf));
        uint32_t w0 = (__float_as_uint(e0) >> 16) | (__float_as_uint(e1) & 0xFFFF0000u);
        uint32_t w1 = (__float_as_uint(e2) >> 16) | (__float_as_uint(e3) & 0xFFFF0000u);
        int q = w * 64 + qt * 16 + l15;
        *(uint2*)&Pl[q][jt * 16 + lg * 4] = make_uint2(w0, w1);
      }
    }
    #pragma unroll
    for (int ks2 = 0; ks2 < 2; ++ks2) {
      bf16x8 vf = *(const bf16x8*)&vt[l15][jc * 64 + ks2 * 32 + lg * 8];
      #pragma unroll
      for (int qt = 0; qt < 4; ++qt) {
        bf16x8 pf = *(const bf16x8*)&Pl[w * 64 + qt * 16 + l15][ks2 * 32 + lg * 8];
        acc_o[qt] = __builtin_amdgcn_mfma_f32_16x16x32_bf16(pf, vf, acc_o[qt], 0, 0, 0);
      }
    }
  }
  int src = ((lane & 48) + 8) << 2;
  int p = l15;
  int t_l = b * 216 + (bz + (p >> 2)) * 36 + (by + ((p >> 1) & 1)) * 6 + (bx + (p & 1));
  #pragma unroll
  for (int qt = 0; qt < 4; ++qt) {
    #pragma unroll
    for (int r = 0; r < 4; ++r) {
      float den = __int_as_float(__builtin_amdgcn_ds_bpermute(src, __float_as_int(acc_o[qt][r])));
      if (p < 8) {
        int q = w * 64 + qt * 16 + lg * 4 + r;
        o_buf[(size_t)t_l * 1024 + (q << 2) + h] = bf16_rne(acc_o[qt][r] / den);
      }
    }
  }
}

// ---------------------------------------------------------------- L4: split-K wo GEMM + global wo rider
__global__ __launch_bounds__(256) void k_gemm_sk_fused(
    const u16* __restrict__ A, const u16* __restrict__ BT, float* __restrict__ Cp,
    const float* __restrict__ g_o, const float* __restrict__ wo,
    float* __restrict__ part) {
  __shared__ __align__(16) char smem[65536];
  int bid = blockIdx.x, tid = threadIdx.x;
  if (bid < 216) {
    const int M = 1728, N = 256, K = 1024;
    u16* aL = (u16*)smem;
    u16* bL = (u16*)smem + 16384;
    int rowblk = (bid % 27) * 64, colblk = ((bid / 27) & 3) * 64;
    int kz = bid / 108;
    float* C = Cp + (size_t)kz * M * N;
    int lane = tid & 63, w = tid >> 6;
    int wr = (w >> 1) * 32, wc = (w & 1) * 32;
    int fm = lane & 15, lg = lane >> 4;
    f32x4 acc[2][2] = {};
    #pragma unroll 1
    for (int step = 0; step < 2; ++step) {
      int kt = kz * 512 + step * 256;
      __syncthreads();
      stage64x256(A + (size_t)rowblk * K + kt, K, aL, w, lane);
      stage64x256(BT + (size_t)colblk * K + kt, K, bL, w, lane);
      __syncthreads();
      #pragma unroll
      for (int kk = 0; kk < 8; ++kk) {
        int k16 = kk * 4 + lg;
        bf16x8 bn0 = lread(bL, wc + fm, k16);
        bf16x8 bn1 = lread(bL, wc + 16 + fm, k16);
        bf16x8 af0 = lread(aL, wr + fm, k16);
        bf16x8 af1 = lread(aL, wr + 16 + fm, k16);
        acc[0][0] = __builtin_amdgcn_mfma_f32_16x16x32_bf16(af0, bn0, acc[0][0], 0, 0, 0);
        acc[0][1] = __builtin_amdgcn_mfma_f32_16x16x32_bf16(af0, bn1, acc[0][1], 0, 0, 0);
        acc[1][0] = __builtin_amdgcn_mfma_f32_16x16x32_bf16(af1, bn0, acc[1][0], 0, 0, 0);
        acc[1][1] = __builtin_amdgcn_mfma_f32_16x16x32_bf16(af1, bn1, acc[1][1], 0, 0, 0);
      }
    }
    __syncthreads();
    float* ct = (float*)smem;       // [64][64] fp32 C-tile (16KB)
    #pragma unroll
    for (int mi = 0; mi < 2; ++mi)
      #pragma unroll
      for (int ni = 0; ni < 2; ++ni)
        #pragma unroll
        for (int r = 0; r < 4; ++r)
          ct[(wr + mi * 16 + lg * 4 + r) * 64 + wc + ni * 16 + fm] = acc[mi][ni][r];
    __syncthreads();
    #pragma unroll
    for (int pass = 0; pass < 4; ++pass) {
      int id = pass * 256 + tid;
      int r = id >> 4, u = id & 15;
      *(float4*)&C[(size_t)(rowblk + r) * N + colblk + u * 4] = *(float4*)&ct[r * 64 + u * 4];
    }
  } else {
    float* os = (float*)smem;               // 8 x 32
    int kc = bid - 216;
    os[tid] = g_o[(tid >> 5) * 1024 + kc * 32 + (tid & 31)];
    __syncthreads();
    float acc[8] = {};
    #pragma unroll
    for (int kk = 0; kk < 32; ++kk) {
      float w = wo[(size_t)(kc * 32 + kk) * 256 + tid];
      #pragma unroll
      for (int b = 0; b < 8; ++b) acc[b] = fmaf(os[b * 32 + kk], w, acc[b]);
    }
    #pragma unroll
    for (int b = 0; b < 8; ++b) part[kc * 2048 + b * 256 + tid] = acc[b];
  }
}

// ---------------------------------------------------------------- L5: local LN2 + global LN2 rider
__global__ __launch_bounds__(256) void k_l_ln2_fused(
    const float* __restrict__ proj0, const float* __restrict__ proj1,
    const float* __restrict__ res, const float* __restrict__ g2,
    const float* __restrict__ b2, u16* __restrict__ t2b,
    const float* __restrict__ part, const float* __restrict__ g_part,
    const float* __restrict__ tw_, const float* __restrict__ tb_,
    const float* __restrict__ gg2, const float* __restrict__ gb2,
    float* __restrict__ t2g) {
  __shared__ float s2v[2][4];
  int bid = blockIdx.x, c = threadIdx.x;
  if (bid < 1728) {
    int t = bid;
    float v = proj0[t * 256 + c] + proj1[t * 256 + c] + res[t * 256 + c];
    float r2[2];
    blk_sum2(v, v * v, r2, s2v);
    float mu = r2[0] * (1.f / 256.f);
    float var = r2[1] * (1.f / 256.f) - mu * mu;
    t2b[t * 256 + c] = bf16_rne((v - mu) * rsqrtf(var + 1e-6f) * g2[c] + b2[c]);
  } else {
    int b = bid - 1728;
    float a = (c < 216) ? g_part[b * 216 + c] : 0.f;
    float m = blk_sum(a, (float*)s2v) * (1.f / 442368.f);
    float v = m * tw_[c] + tb_[c];
    #pragma unroll
    for (int kc = 0; kc < 32; ++kc) v += part[kc * 2048 + b * 256 + c];
    float r2[2];
    blk_sum2(v, v * v, r2, s2v);
    float mu = r2[0] * (1.f / 256.f);
    float var = r2[1] * (1.f / 256.f) - mu * mu;
    t2g[b * 256 + c] = (v - mu) * rsqrtf(var + 1e-6f) * gg2[c] + gb2[c];
  }
}

// ---------------------------------------------------------------- L6: global mo (standalone)
__global__ __launch_bounds__(256) void k_g_mo(
    const float* __restrict__ t2g, const float* __restrict__ mow,
    const float* __restrict__ mob, float* __restrict__ g_vec) {
  __shared__ float ts[2048];
  int tid = threadIdx.x;
  for (int i = tid; i < 2048; i += 256) ts[i] = t2g[i];
  __syncthreads();
  int ol = tid >> 5, cs = tid & 31;
  int o = blockIdx.x * 8 + ol;
  const float* wrow = mow + (size_t)o * 256;
  float acc[8] = {};
  #pragma unroll
  for (int i = 0; i < 8; ++i) {
    float w = wrow[i * 32 + cs];
    #pragma unroll
    for (int b = 0; b < 8; ++b) acc[b] = fmaf(ts[b * 256 + i * 32 + cs], w, acc[b]);
  }
  #pragma unroll
  for (int b = 0; b < 8; ++b) {
    float v = acc[b];
    #pragma unroll
    for (int off = 16; off > 0; off >>= 1) v += __shfl_down(v, off, 32);
    if (cs == 0) g_vec[b * 256 + o] = gelu_f(v + mob[o]);
  }
}

// ---------------------------------------------------------------- L7: mo GEMM + fused final
__global__ __launch_bounds__(256) void k_gemm_mo_final(
    const u16* __restrict__ A, const u16* __restrict__ BT,
    const float* __restrict__ x, const float* __restrict__ gvec,
    const float* __restrict__ mob, float* __restrict__ out) {
  __shared__ __align__(16) char smem[65536];
  u16* aL = (u16*)smem;
  u16* bL = (u16*)smem + 16384;
  float (*ct)[65] = (float(*)[65])smem;       // reused after k-loop
  const int K = 256;
  int tid = threadIdx.x;
  int rowblk = blockIdx.x * 64, colblk = blockIdx.y * 64;
  int lane = tid & 63, w = tid >> 6;
  int wr = (w >> 1) * 32, wc = (w & 1) * 32;
  int fm = lane & 15, lg = lane >> 4;
  stage64x256(A + (size_t)rowblk * K, K, aL, w, lane);
  stage64x256(BT + (size_t)colblk * K, K, bL, w, lane);
  __syncthreads();
  f32x4 acc[2][2] = {};
  #pragma unroll
  for (int kk = 0; kk < 8; ++kk) {
    int k16 = kk * 4 + lg;
    bf16x8 bn0 = lread(bL, wc + fm, k16);
    bf16x8 bn1 = lread(bL, wc + 16 + fm, k16);
    bf16x8 af0 = lread(aL, wr + fm, k16);
    bf16x8 af1 = lread(aL, wr + 16 + fm, k16);
    acc[0][0] = __builtin_amdgcn_mfma_f32_16x16x32_bf16(af0, bn0, acc[0][0], 0, 0, 0);
    acc[0][1] = __builtin_amdgcn_mfma_f32_16x16x32_bf16(af0, bn1, acc[0][1], 0, 0, 0);
    acc[1][0] = __builtin_amdgcn_mfma_f32_16x16x32_bf16(af1, bn0, acc[1][0], 0, 0, 0);
    acc[1][1] = __builtin_amdgcn_mfma_f32_16x16x32_bf16(af1, bn1, acc[1][1], 0, 0, 0);
  }
  __syncthreads();                            // LDS safe to repurpose
  int row_l0 = wr + lg * 4;
  #pragma unroll
  for (int mi = 0; mi < 2; ++mi)
    #pragma unroll
    for (int ni = 0; ni < 2; ++ni)
      #pragma unroll
      for (int r = 0; r < 4; ++r)
        ct[row_l0 + mi * 16 + r][wc + ni * 16 + fm] = acc[mi][ni][r];
  __syncthreads();
  int s_l = tid & 63;
  #pragma unroll 4
  for (int pass = 0; pass < 16; ++pass) {
    int col_l = (tid >> 6) * 16 + pass;
    int row = rowblk + s_l, col = colblk + col_l;
    int b = row / 216, s = row - b * 216;
    size_t idx = (size_t)b * 55296 + (size_t)col * 216 + s;
    out[idx] = x[idx] + gvec[b * 256 + col] + gelu_f(ct[s_l][col_l] + mob[col]);
  }
}

// ---------------------------------------------------------------- launcher
extern "C" void kernel_launch(void* const* d_in, const int* in_sizes, int n_in,
                              void* d_out, int out_size, void* d_ws, size_t ws_size,
                              hipStream_t stream) {
  const float* x     = (const float*)d_in[0];
  const float* g_tw  = (const float*)d_in[1];
  const float* g_tb  = (const float*)d_in[2];
  const float* g_l1g = (const float*)d_in[3];
  const float* g_l1b = (const float*)d_in[4];
  const float* g_wq  = (const float*)d_in[5];
  const float* g_wk  = (const float*)d_in[6];
  const float* g_wv  = (const float*)d_in[7];
  const float* g_wo  = (const float*)d_in[8];
  const float* g_l2g = (const float*)d_in[9];
  const float* g_l2b = (const float*)d_in[10];
  const float* g_mow = (const float*)d_in[11];
  const float* g_mob = (const float*)d_in[12];
  const float* l_pw  = (const float*)d_in[13];
  const float* l_pb  = (const float*)d_in[14];
  const float* l_l1g = (const float*)d_in[15];
  const float* l_l1b = (const float*)d_in[16];
  const float* l_wq  = (const float*)d_in[17];
  const float* l_wk  = (const float*)d_in[18];
  const float* l_wv  = (const float*)d_in[19];
  const float* l_wo  = (const float*)d_in[20];
  const float* l_l2g = (const float*)d_in[21];
  const float* l_l2b = (const float*)d_in[22];
  const float* l_mow = (const float*)d_in[23];
  const float* l_mob = (const float*)d_in[24];
  float* out = (float*)d_out;
  float* ws  = (float*)d_ws;

  // workspace layout (float offsets; bf16 regions hold 2 vals per float slot)
  float* g_qkv  = ws + 4096;     // 24576
  float* g_o    = ws + 28672;    // 8192
  float* g_vec  = ws + 36864;    // 2048
  float* g_part = ws + 38912;    // 1728
  float* res    = ws + 40960;    // 442368 f32
  u16*   eln_bf = (u16*)(ws + 483328);   // 442368 u16
  u16*   WcatT  = (u16*)(ws + 704512);   // 786432 u16 [3072 j][256 c]
  u16*   woT    = (u16*)(ws + 1097728);  // 262144 u16 [256][1024]
  u16*   moB    = (u16*)(ws + 1228800);  // 65536  u16
  u16*   qkvb   = (u16*)(ws + 1261568);  // 5308416 u16 (bf16 qkv)
  u16*   o_buf  = (u16*)(ws + 6569984);  // 1769472 u16
  float* proj   = ws + 7454720;  // 2 x 442368 f32 (split-K partials)
  u16*   t2b    = (u16*)(ws + 8339456);  // 442368 u16
  float* part_wo= ws + 8560640;  // 65536 (32 kc x 8 b x 256 c)
  float* t2g    = ws + 8626176;  // 2048

  // L1: local tok + weight prep rider
  k_l_tok_prep<<<3008, 256, 0, stream>>>(x, l_pw, l_pb, l_l1g, l_l1b,
                                         res, eln_bf, g_part,
                                         l_wq, l_wk, l_wv, l_wo, l_mow,
                                         WcatT, woT, moB);
  // L2a: local qkv GEMM (chunk-major preload, XCD swizzle)
  k_gemm_qkv<<<1296, 256, 0, stream>>>(eln_bf, WcatT, qkvb);
  // L2b: global tok+LN1+qkv rider (independent of L2a)
  k_g_qkv<<<48, 256, 0, stream>>>(g_part, g_tw, g_tb, g_l1g, g_l1b,
                                  g_wq, g_wk, g_wv, g_qkv);
  // L3: local attention + global attn rider
  k_l_attn_fused<<<896, 256, 0, stream>>>(qkvb, o_buf, g_qkv, g_o);
  // L4: split-K wo GEMM + global wo rider
  k_gemm_sk_fused<<<248, 256, 0, stream>>>(o_buf, woT, proj, g_o, g_wo, part_wo);
  // L5: local LN2 + global LN2 rider
  k_l_ln2_fused<<<1736, 256, 0, stream>>>(proj, proj + 442368, res,
                                          l_l2g, l_l2b, t2b,
                                          part_wo, g_part, g_tw, g_tb,
                                          g_l2g, g_l2b, t2g);
  // L6: global mo
  k_g_mo<<<32, 256, 0, stream>>>(t2g, g_mow, g_mob, g_vec);
  // L7: mo GEMM + fused final (coalesced epilogue)
  k_gemm_mo_final<<<dim3(27, 4), 256, 0, stream>>>(t2b, moB, x, g_vec, l_mob, out);
}

// Round 15
// 93.371 us; speedup vs baseline: 1.2551x; 1.2551x over previous
//
#include <hip/hip_runtime.h>
#include <stdint.h>
#include <math.h>

#define DEVFN __device__ __forceinline__
typedef unsigned short u16;
typedef short bf16x8 __attribute__((ext_vector_type(8)));
typedef float f32x4  __attribute__((ext_vector_type(4)));

// ---------------------------------------------------------------- helpers
DEVFN float blk_sum(float v, float* s4) {          // 256-thread block sum
  #pragma unroll
  for (int o = 32; o > 0; o >>= 1) v += __shfl_down(v, o, 64);
  __syncthreads();
  if ((threadIdx.x & 63) == 0) s4[threadIdx.x >> 6] = v;
  __syncthreads();
  return s4[0] + s4[1] + s4[2] + s4[3];
}

DEVFN void blk_sum3(float a, float b, float c, float* out, float (*s)[4]) {
  #pragma unroll
  for (int o = 32; o > 0; o >>= 1) {
    a += __shfl_down(a, o, 64);
    b += __shfl_down(b, o, 64);
    c += __shfl_down(c, o, 64);
  }
  __syncthreads();
  if ((threadIdx.x & 63) == 0) {
    int wi = threadIdx.x >> 6;
    s[0][wi] = a; s[1][wi] = b; s[2][wi] = c;
  }
  __syncthreads();
  out[0] = s[0][0] + s[0][1] + s[0][2] + s[0][3];
  out[1] = s[1][0] + s[1][1] + s[1][2] + s[1][3];
  out[2] = s[2][0] + s[2][1] + s[2][2] + s[2][3];
}

DEVFN void blk_sum2(float a, float b, float* out, float (*s)[4]) {
  #pragma unroll
  for (int o = 32; o > 0; o >>= 1) {
    a += __shfl_down(a, o, 64);
    b += __shfl_down(b, o, 64);
  }
  __syncthreads();
  if ((threadIdx.x & 63) == 0) {
    int wi = threadIdx.x >> 6;
    s[0][wi] = a; s[1][wi] = b;
  }
  __syncthreads();
  out[0] = s[0][0] + s[0][1] + s[0][2] + s[0][3];
  out[1] = s[1][0] + s[1][1] + s[1][2] + s[1][3];
}

DEVFN float gelu_f(float x) {
  return 0.5f * x * (1.f + erff(x * 0.7071067811865475f));
}

DEVFN u16 bf16_rne(float f) {                      // fp32 -> bf16 round-nearest-even
  uint32_t u = __float_as_uint(f);
  return (u16)((u + 0x7fffu + ((u >> 16) & 1u)) >> 16);
}

DEVFN float bf2f(u16 v) { return __uint_as_float(((uint32_t)v) << 16); }

// async global->LDS, 16B/lane; LDS dest = wave-uniform base + lane*16.
DEVFN void gload16(const u16* g, u16* l) {
  auto gp = (const __attribute__((address_space(1))) uint32_t*)(uintptr_t)g;
  auto lp = (__attribute__((address_space(3))) uint32_t*)(uintptr_t)l;
  __builtin_amdgcn_global_load_lds(gp, lp, 16, 0, 0);
}

// legacy helpers (L4/L7): row-major [64][256] with XOR source-side swizzle
DEVFN void stage64x256(const u16* G, size_t gstride, u16* L, int w, int lane) {
  #pragma unroll
  for (int i = 0; i < 8; ++i) {
    int row = w * 16 + 2 * i + (lane >> 5);
    int c16 = (lane & 31) ^ (row & 7);
    gload16(G + (size_t)row * gstride + c16 * 8, L + (w * 16 + 2 * i) * 256);
  }
}
DEVFN bf16x8 lread(const u16* L, int row, int k16) {
  return *(const bf16x8*)&L[row * 256 + ((k16 ^ (row & 7)) << 3)];
}

// ---------------------------------------------------------------- L1: local tok + weight prep rider
DEVFN void trc_tile(const float* __restrict__ in, u16* __restrict__ out,
                    int R, int C, int r0, int c0, float (*tile)[33], int tid) {
  int tx = tid & 31, ty = tid >> 5;
  for (int i = ty; i < 32; i += 8) tile[i][tx] = in[(size_t)(r0 + i) * C + c0 + tx];
  __syncthreads();
  for (int i = ty; i < 32; i += 8)
    out[(size_t)(c0 + i) * R + r0 + tx] = bf16_rne(tile[tx][i]);
}

__global__ __launch_bounds__(256) void k_l_tok_prep(
    const float* __restrict__ x, const float* __restrict__ pw,
    const float* __restrict__ pb, const float* __restrict__ g1,
    const float* __restrict__ b1, float* __restrict__ res,
    u16* __restrict__ eln_bf, float* __restrict__ g_part,
    const float* __restrict__ wq, const float* __restrict__ wk,
    const float* __restrict__ wv, const float* __restrict__ wo,
    const float* __restrict__ mow, u16* __restrict__ WcatT,
    u16* __restrict__ woT, u16* __restrict__ moB) {
  __shared__ __align__(16) char smem[8448];
  int bid0 = blockIdx.x, tid = threadIdx.x;
  if (bid0 < 1728) {
    float* pws = (float*)smem;
    float (*s3)[4] = (float(*)[4])(smem + 256);
    int t = bid0;
    int b = t / 216, s = t % 216;
    int z = s / 36, y = (s / 6) % 6, xx = s % 6;
    int d = z >> 1, p1 = z & 1, hh = y >> 1, p2 = y & 1, ww = xx >> 1, p3 = xx & 1;
    int p = p1 * 4 + p2 * 2 + p3;
    int c = tid;
    if (c < 64) pws[c] = pw[c];
    __syncthreads();
    const float* xb = x + (b * 256 + c) * 216 + (2 * d) * 36 + (2 * hh) * 6 + 2 * ww;
    float v = pb[p];
    float xs = 0.f;
    #pragma unroll
    for (int q1 = 0; q1 < 2; ++q1)
      #pragma unroll
      for (int q2 = 0; q2 < 2; ++q2)
        #pragma unroll
        for (int q3 = 0; q3 < 2; ++q3) {
          float xv = xb[q1 * 36 + q2 * 6 + q3];
          xs += xv;
          v += xv * pws[p * 8 + (q1 * 4 + q2 * 2 + q3)];
        }
    float r3[3];
    blk_sum3(xs, v, v * v, r3, s3);
    if (c == 0) g_part[t] = r3[0];
    res[t * 256 + c] = v;
    float mu = r3[1] * (1.f / 256.f);
    float var = r3[2] * (1.f / 256.f) - mu * mu;
    eln_bf[t * 256 + c] = bf16_rne((v - mu) * rsqrtf(var + 1e-6f) * g1[c] + b1[c]);
  } else {
    float (*tile)[33] = (float(*)[33])smem;
    int bid = bid0 - 1728;
    if (bid < 768) {            // wq/wk/wv: [256][1024] -> [1024][256]
      int which = bid >> 8, b2 = bid & 255;
      const float* in = (which == 0) ? wq : (which == 1) ? wk : wv;
      u16* out = WcatT + which * 262144;
      int r0 = (b2 & 7) * 32, c0 = (b2 >> 3) * 32;
      trc_tile(in, out, 256, 1024, r0, c0, tile, tid);
    } else if (bid < 1024) {    // wo: [1024][256] -> [256][1024]
      int b2 = bid - 768;
      int r0 = (b2 & 31) * 32, c0 = (b2 >> 5) * 32;
      trc_tile(wo, woT, 1024, 256, r0, c0, tile, tid);
    } else {                    // mo_w cast
      int i = (bid - 1024) * 256 + tid;
      moB[i] = bf16_rne(mow[i]);
    }
  }
}

// ---------------------------------------------------------------- L2: global qkv rider FIRST + local qkv GEMM
// blocks [0,48): fused global tok+LN1+qkv (8-wide batched weight loads).
// blocks [48,1344): bf16 MFMA GEMM (M=1728,N=3072,K=256), full-K single-drain
// chunk-major LDS preload (bank-clean), XCD-chunked swizzle, uint4 C stores.
__global__ __launch_bounds__(256) void k_gemm_qkv_fused(
    const u16* __restrict__ A, const u16* __restrict__ BT, u16* __restrict__ C,
    const float* __restrict__ g_part, const float* __restrict__ tw_,
    const float* __restrict__ tb_, const float* __restrict__ g1,
    const float* __restrict__ b1, const float* __restrict__ wq,
    const float* __restrict__ wk, const float* __restrict__ wv,
    float* __restrict__ gqkv) {
  __shared__ __align__(16) char smem[65536];
  int bid = blockIdx.x, tid = threadIdx.x;
  if (bid < 48) {                 // ---- rider: runs concurrent with GEMM
    float* ts = (float*)smem;
    float (*red)[4][8] = (float(*)[4][8])(smem + 8192);
    float* s4 = (float*)(smem + 16384);
    float* m_s = (float*)(smem + 16400);
    float tw = tw_[tid], tb = tb_[tid], gg = g1[tid], bb = b1[tid];
    float S1 = blk_sum(tw, s4);
    float S2 = blk_sum(tw * tw, s4);
    float S3 = blk_sum(tb, s4);
    float S4 = blk_sum(tb * tb, s4);
    float S5 = blk_sum(tw * tb, s4);
    {
      int b = tid >> 5, sl = tid & 31;
      float a = 0.f;
      for (int k = sl; k < 216; k += 32) a += g_part[b * 216 + k];
      #pragma unroll
      for (int o = 16; o > 0; o >>= 1) a += __shfl_down(a, o, 32);
      if (sl == 0) m_s[b] = a * (1.f / 442368.f);   // 8 * 55296 over-count
    }
    __syncthreads();
    #pragma unroll
    for (int b = 0; b < 8; ++b) {
      float m = m_s[b];
      float mu = (m * S1 + S3) * (1.f / 256.f);
      float var = (m * m * S2 + 2.f * m * S5 + S4) * (1.f / 256.f) - mu * mu;
      ts[b * 256 + tid] = (m * tw + tb - mu) * rsqrtf(var + 1e-6f) * gg + bb;
    }
    __syncthreads();
    int col0 = bid * 64;
    int cl = tid & 63, kq = tid >> 6;
    int col = col0 + cl;
    int m = col >> 10, cc = col & 1023;
    const float* W = (m == 0) ? wq : (m == 1) ? wk : wv;
    float acc[8] = {};
    for (int c0 = kq * 64; c0 < kq * 64 + 64; c0 += 8) {
      float wbuf[8];
      #pragma unroll
      for (int j = 0; j < 8; ++j) wbuf[j] = W[(c0 + j) * 1024 + cc];  // 8 in flight
      #pragma unroll
      for (int j = 0; j < 8; ++j) {
        float w = wbuf[j];
        #pragma unroll
        for (int b = 0; b < 8; ++b) acc[b] = fmaf(ts[b * 256 + c0 + j], w, acc[b]);
      }
    }
    #pragma unroll
    for (int b = 0; b < 8; ++b) red[cl][kq][b] = acc[b];
    __syncthreads();
    if (kq == 0) {
      #pragma unroll
      for (int b = 0; b < 8; ++b)
        gqkv[b * 3072 + col] = red[cl][0][b] + red[cl][1][b] + red[cl][2][b] + red[cl][3][b];
    }
  } else {
    const int N = 3072, K = 256;
    u16* aL = (u16*)smem;          // chunk-major [32][64 rows][16B]
    u16* bL = (u16*)smem + 16384;
    int t0 = bid - 48;
    int tile = (t0 & 7) * 162 + (t0 >> 3);   // bijective XCD swizzle (1296=8*162)
    int rowblk = (tile % 27) * 64, colblk = (tile / 27) * 64;
    int lane = tid & 63, w = tid >> 6;
    int wr = (w >> 1) * 32, wc = (w & 1) * 32;
    int fm = lane & 15, lg = lane >> 4;
    #pragma unroll
    for (int i = 0; i < 8; ++i) {
      int c16 = w * 8 + i;                   // uniform chunk per instruction
      gload16(&A[(size_t)(rowblk + lane) * K + c16 * 8], aL + c16 * 512);
      gload16(&BT[(size_t)(colblk + lane) * K + c16 * 8], bL + c16 * 512);
    }
    __syncthreads();                         // single drain of all 16 loads
    f32x4 acc[2][2] = {};
    #pragma unroll
    for (int kk = 0; kk < 8; ++kk) {
      int k16 = kk * 4 + lg;
      bf16x8 bn0 = *(const bf16x8*)&bL[k16 * 512 + (wc + fm) * 8];
      bf16x8 bn1 = *(const bf16x8*)&bL[k16 * 512 + (wc + 16 + fm) * 8];
      bf16x8 af0 = *(const bf16x8*)&aL[k16 * 512 + (wr + fm) * 8];
      bf16x8 af1 = *(const bf16x8*)&aL[k16 * 512 + (wr + 16 + fm) * 8];
      acc[0][0] = __builtin_amdgcn_mfma_f32_16x16x32_bf16(af0, bn0, acc[0][0], 0, 0, 0);
      acc[0][1] = __builtin_amdgcn_mfma_f32_16x16x32_bf16(af0, bn1, acc[0][1], 0, 0, 0);
      acc[1][0] = __builtin_amdgcn_mfma_f32_16x16x32_bf16(af1, bn0, acc[1][0], 0, 0, 0);
      acc[1][1] = __builtin_amdgcn_mfma_f32_16x16x32_bf16(af1, bn1, acc[1][1], 0, 0, 0);
    }
    __syncthreads();                         // LDS safe to repurpose
    u16* ct = aL;                            // [64][72] bf16 (padded rows)
    #pragma unroll
    for (int mi = 0; mi < 2; ++mi)
      #pragma unroll
      for (int ni = 0; ni < 2; ++ni)
        #pragma unroll
        for (int r = 0; r < 4; ++r)
          ct[(wr + mi * 16 + lg * 4 + r) * 72 + wc + ni * 16 + fm] = bf16_rne(acc[mi][ni][r]);
    __syncthreads();
    #pragma unroll
    for (int pass = 0; pass < 2; ++pass) {
      int id = pass * 256 + tid;
      int r = id >> 3, u = id & 7;
      *(uint4*)&C[(size_t)(rowblk + r) * N + colblk + u * 8] = *(uint4*)&ct[r * 72 + u * 8];
    }
  }
}

// ---------------------------------------------------------------- L3: global attn rider FIRST + local attention
__global__ __launch_bounds__(256) void k_l_attn_fused(
    const u16* __restrict__ qkv, u16* __restrict__ o_buf,
    const float* __restrict__ gq, float* __restrict__ g_o) {
  __shared__ __align__(16) uint4 Qb[256], Kb[256];
  __shared__ __align__(16) u16 vt[16][264];
  __shared__ __align__(16) u16 Pl[256][72];
  __shared__ float rqA[64][4], rkA[64][4], rlq[64][4], rlk[64][4], s_ab[2];
  int bid = blockIdx.x, tid = threadIdx.x;
  if (bid < 32) {                         // ---- global attn rider (first)
    float* ks = (float*)Qb;               // overlay: 1KB
    float* vs = ks + 256;
    float* s4 = (float*)Kb;
    int b = bid >> 2, h = bid & 3;
    int i = tid;
    const float* base = gq + b * 3072 + h * 256;
    float q = base[i];
    float k = base[1024 + i];
    ks[i] = k;
    vs[i] = base[2048 + i];
    float sq  = blk_sum(q, s4);
    float sq2 = blk_sum(q * q, s4);
    float sk  = blk_sum(k, s4);
    float sk2 = blk_sum(k * k, s4);
    float tot  = sq * sk * (1.f / 65536.f);
    float tot2 = sq2 * sk2 * (1.f / 65536.f);
    float rstd = rsqrtf(tot2 - tot * tot + 1e-5f);
    float A = rstd, B = -tot * rstd;
    float den = 0.f, num = 0.f;
    for (int j = 0; j < 256; ++j) {
      float w = __expf(fmaf(q * ks[j], A, B));
      den += w; num += w * vs[j];
    }
    g_o[b * 1024 + (i << 2) + h] = num / den;
    return;
  }
  int nb = bid - 32;
  int n = nb >> 2, h = nb & 3;
  int b = n / 27, patch = n % 27;
  int bz = 2 * (patch / 9), by = 2 * ((patch / 3) % 3), bx = 2 * (patch % 3);
  {
    int c = tid;
    u16 qv[8], kv[8], vv[8];
    #pragma unroll
    for (int p = 0; p < 8; ++p) {
      int t_l = b * 216 + (bz + (p >> 2)) * 36 + (by + ((p >> 1) & 1)) * 6 + (bx + (p & 1));
      const u16* row = qkv + (size_t)t_l * 3072 + (c << 2) + h;
      qv[p] = row[0]; kv[p] = row[1024]; vv[p] = row[2048];
    }
    uint32_t qw[4], kw[4];
    #pragma unroll
    for (int i = 0; i < 4; ++i) {
      qw[i] = (uint32_t)qv[2 * i] | ((uint32_t)qv[2 * i + 1] << 16);
      kw[i] = (uint32_t)kv[2 * i] | ((uint32_t)kv[2 * i + 1] << 16);
    }
    Qb[c] = make_uint4(qw[0], qw[1], qw[2], qw[3]);
    Kb[c] = make_uint4(kw[0], kw[1], kw[2], kw[3]);
    #pragma unroll
    for (int p = 0; p < 8; ++p) vt[p][c] = vv[p];
    vt[8][c] = 0x3F80u;                  // bf16(1.0): denominator ones-row
    #pragma unroll
    for (int r2 = 9; r2 < 16; ++r2) vt[r2][c] = 0;
  }
  __syncthreads();
  {
    int p = tid & 63, chunk = tid >> 6;
    int d = p >> 3, e = p & 7;
    float aq = 0.f, ak = 0.f, lq = 0.f, lk = 0.f;
    for (int cc = chunk * 64; cc < chunk * 64 + 64; ++cc) {
      const u16* qr = (const u16*)&Qb[cc];
      const u16* kr = (const u16*)&Kb[cc];
      float qd = bf2f(qr[d]), qe = bf2f(qr[e]);
      float kd = bf2f(kr[d]), ke = bf2f(kr[e]);
      aq = fmaf(qd, qe, aq); ak = fmaf(kd, ke, ak);
      if (e == 0) { lq += qd; lk += kd; }
    }
    rqA[p][chunk] = aq; rkA[p][chunk] = ak; rlq[p][chunk] = lq; rlk[p][chunk] = lk;
    __syncthreads();
    if (tid < 64) {
      float gq2 = rqA[tid][0] + rqA[tid][1] + rqA[tid][2] + rqA[tid][3];
      float gk = rkA[tid][0] + rkA[tid][1] + rkA[tid][2] + rkA[tid][3];
      float vprod = gq2 * gk, vmu = 0.f;
      if ((tid & 7) == 0) {
        float slq = rlq[tid][0] + rlq[tid][1] + rlq[tid][2] + rlq[tid][3];
        float slk = rlk[tid][0] + rlk[tid][1] + rlk[tid][2] + rlk[tid][3];
        vmu = slq * slk;
      }
      #pragma unroll
      for (int o = 32; o > 0; o >>= 1) {
        vprod += __shfl_down(vprod, o, 64);
        vmu   += __shfl_down(vmu, o, 64);
      }
      if (tid == 0) {
        float mu = vmu * (1.f / 65536.f), m2 = vprod * (1.f / 65536.f);
        float rstd = rsqrtf(m2 - mu * mu + 1e-5f);
        s_ab[0] = rstd; s_ab[1] = -mu * rstd;
      }
    }
    __syncthreads();
  }
  float Af = s_ab[0], Bf = s_ab[1];
  int lane = tid & 63, w = tid >> 6;
  int l15 = lane & 15, lg = lane >> 4;
  bf16x8 qf[4];
  #pragma unroll
  for (int qt = 0; qt < 4; ++qt)
    qf[qt] = *(const bf16x8*)&Qb[w * 64 + qt * 16 + l15];
  f32x4 acc_o[4] = {};
  #pragma unroll 1
  for (int jc = 0; jc < 4; ++jc) {
    bf16x8 kf[4];
    #pragma unroll
    for (int jt = 0; jt < 4; ++jt) {
      bf16x8 z = {};
      if (lg == 0) z = *(const bf16x8*)&Kb[jc * 64 + jt * 16 + l15];
      kf[jt] = z;
    }
    #pragma unroll
    for (int jt = 0; jt < 4; ++jt) {
      #pragma unroll
      for (int qt = 0; qt < 4; ++qt) {
        f32x4 zc = {};
        f32x4 s = __builtin_amdgcn_mfma_f32_16x16x32_bf16(kf[jt], qf[qt], zc, 0, 0, 0);
        float e0 = __expf(fmaf(s[0], Af, Bf));
        float e1 = __expf(fmaf(s[1], Af, Bf));
        float e2 = __expf(fmaf(s[2], Af, Bf));
        float e3 = __expf(fmaf(s[3], Af, Bf));
        uint32_t w0 = (__float_as_uint(e0) >> 16) | (__float_as_uint(e1) & 0xFFFF0000u);
        uint32_t w1 = (__float_as_uint(e2) >> 16) | (__float_as_uint(e3) & 0xFFFF0000u);
        int q = w * 64 + qt * 16 + l15;
        *(uint2*)&Pl[q][jt * 16 + lg * 4] = make_uint2(w0, w1);
      }
    }
    #pragma unroll
    for (int ks2 = 0; ks2 < 2; ++ks2) {
      bf16x8 vf = *(const bf16x8*)&vt[l15][jc * 64 + ks2 * 32 + lg * 8];
      #pragma unroll
      for (int qt = 0; qt < 4; ++qt) {
        bf16x8 pf = *(const bf16x8*)&Pl[w * 64 + qt * 16 + l15][ks2 * 32 + lg * 8];
        acc_o[qt] = __builtin_amdgcn_mfma_f32_16x16x32_bf16(pf, vf, acc_o[qt], 0, 0, 0);
      }
    }
  }
  int src = ((lane & 48) + 8) << 2;
  int p = l15;
  int t_l = b * 216 + (bz + (p >> 2)) * 36 + (by + ((p >> 1) & 1)) * 6 + (bx + (p & 1));
  #pragma unroll
  for (int qt = 0; qt < 4; ++qt) {
    #pragma unroll
    for (int r = 0; r < 4; ++r) {
      float den = __int_as_float(__builtin_amdgcn_ds_bpermute(src, __float_as_int(acc_o[qt][r])));
      if (p < 8) {
        int q = w * 64 + qt * 16 + lg * 4 + r;
        o_buf[(size_t)t_l * 1024 + (q << 2) + h] = bf16_rne(acc_o[qt][r] / den);
      }
    }
  }
}

// ---------------------------------------------------------------- L4: global wo rider FIRST + split-K wo GEMM
__global__ __launch_bounds__(256) void k_gemm_sk_fused(
    const u16* __restrict__ A, const u16* __restrict__ BT, float* __restrict__ Cp,
    const float* __restrict__ g_o, const float* __restrict__ wo,
    float* __restrict__ part) {
  __shared__ __align__(16) char smem[65536];
  int bid = blockIdx.x, tid = threadIdx.x;
  if (bid < 32) {                           // ---- rider first
    float* os = (float*)smem;               // 8 x 32
    int kc = bid;
    os[tid] = g_o[(tid >> 5) * 1024 + kc * 32 + (tid & 31)];
    __syncthreads();
    float acc[8] = {};
    #pragma unroll
    for (int kk = 0; kk < 32; ++kk) {
      float w = wo[(size_t)(kc * 32 + kk) * 256 + tid];
      #pragma unroll
      for (int b = 0; b < 8; ++b) acc[b] = fmaf(os[b * 32 + kk], w, acc[b]);
    }
    #pragma unroll
    for (int b = 0; b < 8; ++b) part[kc * 2048 + b * 256 + tid] = acc[b];
  } else {
    const int M = 1728, N = 256, K = 1024;
    u16* aL = (u16*)smem;
    u16* bL = (u16*)smem + 16384;
    int bid2 = bid - 32;
    int rowblk = (bid2 % 27) * 64, colblk = ((bid2 / 27) & 3) * 64;
    int kz = bid2 / 108;
    float* C = Cp + (size_t)kz * M * N;
    int lane = tid & 63, w = tid >> 6;
    int wr = (w >> 1) * 32, wc = (w & 1) * 32;
    int fm = lane & 15, lg = lane >> 4;
    f32x4 acc[2][2] = {};
    #pragma unroll 1
    for (int step = 0; step < 2; ++step) {
      int kt = kz * 512 + step * 256;
      __syncthreads();
      stage64x256(A + (size_t)rowblk * K + kt, K, aL, w, lane);
      stage64x256(BT + (size_t)colblk * K + kt, K, bL, w, lane);
      __syncthreads();
      #pragma unroll
      for (int kk = 0; kk < 8; ++kk) {
        int k16 = kk * 4 + lg;
        bf16x8 bn0 = lread(bL, wc + fm, k16);
        bf16x8 bn1 = lread(bL, wc + 16 + fm, k16);
        bf16x8 af0 = lread(aL, wr + fm, k16);
        bf16x8 af1 = lread(aL, wr + 16 + fm, k16);
        acc[0][0] = __builtin_amdgcn_mfma_f32_16x16x32_bf16(af0, bn0, acc[0][0], 0, 0, 0);
        acc[0][1] = __builtin_amdgcn_mfma_f32_16x16x32_bf16(af0, bn1, acc[0][1], 0, 0, 0);
        acc[1][0] = __builtin_amdgcn_mfma_f32_16x16x32_bf16(af1, bn0, acc[1][0], 0, 0, 0);
        acc[1][1] = __builtin_amdgcn_mfma_f32_16x16x32_bf16(af1, bn1, acc[1][1], 0, 0, 0);
      }
    }
    __syncthreads();
    float* ct = (float*)smem;       // [64][64] fp32 C-tile (16KB)
    #pragma unroll
    for (int mi = 0; mi < 2; ++mi)
      #pragma unroll
      for (int ni = 0; ni < 2; ++ni)
        #pragma unroll
        for (int r = 0; r < 4; ++r)
          ct[(wr + mi * 16 + lg * 4 + r) * 64 + wc + ni * 16 + fm] = acc[mi][ni][r];
    __syncthreads();
    #pragma unroll
    for (int pass = 0; pass < 4; ++pass) {
      int id = pass * 256 + tid;
      int r = id >> 4, u = id & 15;
      *(float4*)&C[(size_t)(rowblk + r) * N + colblk + u * 4] = *(float4*)&ct[r * 64 + u * 4];
    }
  }
}

// ---------------------------------------------------------------- L5: global LN2 rider FIRST + local LN2
__global__ __launch_bounds__(256) void k_l_ln2_fused(
    const float* __restrict__ proj0, const float* __restrict__ proj1,
    const float* __restrict__ res, const float* __restrict__ g2,
    const float* __restrict__ b2, u16* __restrict__ t2b,
    const float* __restrict__ part, const float* __restrict__ g_part,
    const float* __restrict__ tw_, const float* __restrict__ tb_,
    const float* __restrict__ gg2, const float* __restrict__ gb2,
    float* __restrict__ t2g) {
  __shared__ float s2v[2][4];
  int bid = blockIdx.x, c = threadIdx.x;
  if (bid < 8) {
    int b = bid;
    float a = (c < 216) ? g_part[b * 216 + c] : 0.f;
    float m = blk_sum(a, (float*)s2v) * (1.f / 442368.f);
    float v = m * tw_[c] + tb_[c];
    #pragma unroll
    for (int kc = 0; kc < 32; ++kc) v += part[kc * 2048 + b * 256 + c];
    float r2[2];
    blk_sum2(v, v * v, r2, s2v);
    float mu = r2[0] * (1.f / 256.f);
    float var = r2[1] * (1.f / 256.f) - mu * mu;
    t2g[b * 256 + c] = (v - mu) * rsqrtf(var + 1e-6f) * gg2[c] + gb2[c];
  } else {
    int t = bid - 8;
    float v = proj0[t * 256 + c] + proj1[t * 256 + c] + res[t * 256 + c];
    float r2[2];
    blk_sum2(v, v * v, r2, s2v);
    float mu = r2[0] * (1.f / 256.f);
    float var = r2[1] * (1.f / 256.f) - mu * mu;
    t2b[t * 256 + c] = bf16_rne((v - mu) * rsqrtf(var + 1e-6f) * g2[c] + b2[c]);
  }
}

// ---------------------------------------------------------------- L6: global mo (standalone)
__global__ __launch_bounds__(256) void k_g_mo(
    const float* __restrict__ t2g, const float* __restrict__ mow,
    const float* __restrict__ mob, float* __restrict__ g_vec) {
  __shared__ float ts[2048];
  int tid = threadIdx.x;
  for (int i = tid; i < 2048; i += 256) ts[i] = t2g[i];
  __syncthreads();
  int ol = tid >> 5, cs = tid & 31;
  int o = blockIdx.x * 8 + ol;
  const float* wrow = mow + (size_t)o * 256;
  float acc[8] = {};
  #pragma unroll
  for (int i = 0; i < 8; ++i) {
    float w = wrow[i * 32 + cs];
    #pragma unroll
    for (int b = 0; b < 8; ++b) acc[b] = fmaf(ts[b * 256 + i * 32 + cs], w, acc[b]);
  }
  #pragma unroll
  for (int b = 0; b < 8; ++b) {
    float v = acc[b];
    #pragma unroll
    for (int off = 16; off > 0; off >>= 1) v += __shfl_down(v, off, 32);
    if (cs == 0) g_vec[b * 256 + o] = gelu_f(v + mob[o]);
  }
}

// ---------------------------------------------------------------- L7: mo GEMM + fused final
__global__ __launch_bounds__(256) void k_gemm_mo_final(
    const u16* __restrict__ A, const u16* __restrict__ BT,
    const float* __restrict__ x, const float* __restrict__ gvec,
    const float* __restrict__ mob, float* __restrict__ out) {
  __shared__ __align__(16) char smem[65536];
  u16* aL = (u16*)smem;
  u16* bL = (u16*)smem + 16384;
  float (*ct)[65] = (float(*)[65])smem;       // reused after k-loop
  const int K = 256;
  int tid = threadIdx.x;
  int rowblk = blockIdx.x * 64, colblk = blockIdx.y * 64;
  int lane = tid & 63, w = tid >> 6;
  int wr = (w >> 1) * 32, wc = (w & 1) * 32;
  int fm = lane & 15, lg = lane >> 4;
  stage64x256(A + (size_t)rowblk * K, K, aL, w, lane);
  stage64x256(BT + (size_t)colblk * K, K, bL, w, lane);
  __syncthreads();
  f32x4 acc[2][2] = {};
  #pragma unroll
  for (int kk = 0; kk < 8; ++kk) {
    int k16 = kk * 4 + lg;
    bf16x8 bn0 = lread(bL, wc + fm, k16);
    bf16x8 bn1 = lread(bL, wc + 16 + fm, k16);
    bf16x8 af0 = lread(aL, wr + fm, k16);
    bf16x8 af1 = lread(aL, wr + 16 + fm, k16);
    acc[0][0] = __builtin_amdgcn_mfma_f32_16x16x32_bf16(af0, bn0, acc[0][0], 0, 0, 0);
    acc[0][1] = __builtin_amdgcn_mfma_f32_16x16x32_bf16(af0, bn1, acc[0][1], 0, 0, 0);
    acc[1][0] = __builtin_amdgcn_mfma_f32_16x16x32_bf16(af1, bn0, acc[1][0], 0, 0, 0);
    acc[1][1] = __builtin_amdgcn_mfma_f32_16x16x32_bf16(af1, bn1, acc[1][1], 0, 0, 0);
  }
  __syncthreads();                            // LDS safe to repurpose
  int row_l0 = wr + lg * 4;
  #pragma unroll
  for (int mi = 0; mi < 2; ++mi)
    #pragma unroll
    for (int ni = 0; ni < 2; ++ni)
      #pragma unroll
      for (int r = 0; r < 4; ++r)
        ct[row_l0 + mi * 16 + r][wc + ni * 16 + fm] = acc[mi][ni][r];
  __syncthreads();
  int s_l = tid & 63;
  #pragma unroll 4
  for (int pass = 0; pass < 16; ++pass) {
    int col_l = (tid >> 6) * 16 + pass;
    int row = rowblk + s_l, col = colblk + col_l;
    int b = row / 216, s = row - b * 216;
    size_t idx = (size_t)b * 55296 + (size_t)col * 216 + s;
    out[idx] = x[idx] + gvec[b * 256 + col] + gelu_f(ct[s_l][col_l] + mob[col]);
  }
}

// ---------------------------------------------------------------- launcher
extern "C" void kernel_launch(void* const* d_in, const int* in_sizes, int n_in,
                              void* d_out, int out_size, void* d_ws, size_t ws_size,
                              hipStream_t stream) {
  const float* x     = (const float*)d_in[0];
  const float* g_tw  = (const float*)d_in[1];
  const float* g_tb  = (const float*)d_in[2];
  const float* g_l1g = (const float*)d_in[3];
  const float* g_l1b = (const float*)d_in[4];
  const float* g_wq  = (const float*)d_in[5];
  const float* g_wk  = (const float*)d_in[6];
  const float* g_wv  = (const float*)d_in[7];
  const float* g_wo  = (const float*)d_in[8];
  const float* g_l2g = (const float*)d_in[9];
  const float* g_l2b = (const float*)d_in[10];
  const float* g_mow = (const float*)d_in[11];
  const float* g_mob = (const float*)d_in[12];
  const float* l_pw  = (const float*)d_in[13];
  const float* l_pb  = (const float*)d_in[14];
  const float* l_l1g = (const float*)d_in[15];
  const float* l_l1b = (const float*)d_in[16];
  const float* l_wq  = (const float*)d_in[17];
  const float* l_wk  = (const float*)d_in[18];
  const float* l_wv  = (const float*)d_in[19];
  const float* l_wo  = (const float*)d_in[20];
  const float* l_l2g = (const float*)d_in[21];
  const float* l_l2b = (const float*)d_in[22];
  const float* l_mow = (const float*)d_in[23];
  const float* l_mob = (const float*)d_in[24];
  float* out = (float*)d_out;
  float* ws  = (float*)d_ws;

  // workspace layout (float offsets; bf16 regions hold 2 vals per float slot)
  float* g_qkv  = ws + 4096;     // 24576
  float* g_o    = ws + 28672;    // 8192
  float* g_vec  = ws + 36864;    // 2048
  float* g_part = ws + 38912;    // 1728
  float* res    = ws + 40960;    // 442368 f32
  u16*   eln_bf = (u16*)(ws + 483328);   // 442368 u16
  u16*   WcatT  = (u16*)(ws + 704512);   // 786432 u16 [3072 j][256 c]
  u16*   woT    = (u16*)(ws + 1097728);  // 262144 u16 [256][1024]
  u16*   moB    = (u16*)(ws + 1228800);  // 65536  u16
  u16*   qkvb   = (u16*)(ws + 1261568);  // 5308416 u16 (bf16 qkv)
  u16*   o_buf  = (u16*)(ws + 6569984);  // 1769472 u16
  float* proj   = ws + 7454720;  // 2 x 442368 f32 (split-K partials)
  u16*   t2b    = (u16*)(ws + 8339456);  // 442368 u16
  float* part_wo= ws + 8560640;  // 65536 (32 kc x 8 b x 256 c)
  float* t2g    = ws + 8626176;  // 2048

  // L1: local tok + weight prep rider
  k_l_tok_prep<<<3008, 256, 0, stream>>>(x, l_pw, l_pb, l_l1g, l_l1b,
                                         res, eln_bf, g_part,
                                         l_wq, l_wk, l_wv, l_wo, l_mow,
                                         WcatT, woT, moB);
  // L2: global qkv rider (blocks 0-47, concurrent) + local qkv GEMM
  k_gemm_qkv_fused<<<1344, 256, 0, stream>>>(eln_bf, WcatT, qkvb,
                                             g_part, g_tw, g_tb, g_l1g, g_l1b,
                                             g_wq, g_wk, g_wv, g_qkv);
  // L3: global attn rider (blocks 0-31) + local attention
  k_l_attn_fused<<<896, 256, 0, stream>>>(qkvb, o_buf, g_qkv, g_o);
  // L4: global wo rider (blocks 0-31) + split-K wo GEMM
  k_gemm_sk_fused<<<248, 256, 0, stream>>>(o_buf, woT, proj, g_o, g_wo, part_wo);
  // L5: global LN2 rider (blocks 0-7) + local LN2
  k_l_ln2_fused<<<1736, 256, 0, stream>>>(proj, proj + 442368, res,
                                          l_l2g, l_l2b, t2b,
                                          part_wo, g_part, g_tw, g_tb,
                                          g_l2g, g_l2b, t2g);
  // L6: global mo
  k_g_mo<<<32, 256, 0, stream>>>(t2g, g_mow, g_mob, g_vec);
  // L7: mo GEMM + fused final (coalesced epilogue)
  k_gemm_mo_final<<<dim3(27, 4), 256, 0, stream>>>(t2b, moB, x, g_vec, l_mob, out);
}

// Round 16
// 91.323 us; speedup vs baseline: 1.2832x; 1.0224x over previous
//
#include <hip/hip_runtime.h>
#include <stdint.h>
#include <math.h>

#define DEVFN __device__ __forceinline__
typedef unsigned short u16;
typedef short bf16x8 __attribute__((ext_vector_type(8)));
typedef float f32x4  __attribute__((ext_vector_type(4)));

// ---------------------------------------------------------------- helpers
DEVFN float blk_sum(float v, float* s4) {          // 256-thread block sum
  #pragma unroll
  for (int o = 32; o > 0; o >>= 1) v += __shfl_down(v, o, 64);
  __syncthreads();
  if ((threadIdx.x & 63) == 0) s4[threadIdx.x >> 6] = v;
  __syncthreads();
  return s4[0] + s4[1] + s4[2] + s4[3];
}

DEVFN void blk_sum2(float a, float b, float* out, float (*s)[4]) {
  #pragma unroll
  for (int o = 32; o > 0; o >>= 1) {
    a += __shfl_down(a, o, 64);
    b += __shfl_down(b, o, 64);
  }
  __syncthreads();
  if ((threadIdx.x & 63) == 0) {
    int wi = threadIdx.x >> 6;
    s[0][wi] = a; s[1][wi] = b;
  }
  __syncthreads();
  out[0] = s[0][0] + s[0][1] + s[0][2] + s[0][3];
  out[1] = s[1][0] + s[1][1] + s[1][2] + s[1][3];
}

// 17-value fused block sum: one shuffle cascade + one barrier pair
DEVFN void blk_sum17(float* v, float (*s)[4]) {
  #pragma unroll
  for (int o = 32; o > 0; o >>= 1)
    #pragma unroll
    for (int i = 0; i < 17; ++i) v[i] += __shfl_down(v[i], o, 64);
  __syncthreads();
  if ((threadIdx.x & 63) == 0) {
    int wi = threadIdx.x >> 6;
    #pragma unroll
    for (int i = 0; i < 17; ++i) s[i][wi] = v[i];
  }
  __syncthreads();
  #pragma unroll
  for (int i = 0; i < 17; ++i) v[i] = s[i][0] + s[i][1] + s[i][2] + s[i][3];
}

DEVFN float gelu_f(float x) {
  return 0.5f * x * (1.f + erff(x * 0.7071067811865475f));
}

DEVFN u16 bf16_rne(float f) {                      // fp32 -> bf16 round-nearest-even
  uint32_t u = __float_as_uint(f);
  return (u16)((u + 0x7fffu + ((u >> 16) & 1u)) >> 16);
}

DEVFN float bf2f(u16 v) { return __uint_as_float(((uint32_t)v) << 16); }

// async global->LDS, 16B/lane; LDS dest = wave-uniform base + lane*16.
DEVFN void gload16(const u16* g, u16* l) {
  auto gp = (const __attribute__((address_space(1))) uint32_t*)(uintptr_t)g;
  auto lp = (__attribute__((address_space(3))) uint32_t*)(uintptr_t)l;
  __builtin_amdgcn_global_load_lds(gp, lp, 16, 0, 0);
}

// row-major [64][256] staging with XOR source-side swizzle (L4/L7)
DEVFN void stage64x256(const u16* G, size_t gstride, u16* L, int w, int lane) {
  #pragma unroll
  for (int i = 0; i < 8; ++i) {
    int row = w * 16 + 2 * i + (lane >> 5);
    int c16 = (lane & 31) ^ (row & 7);
    gload16(G + (size_t)row * gstride + c16 * 8, L + (w * 16 + 2 * i) * 256);
  }
}
DEVFN bf16x8 lread(const u16* L, int row, int k16) {
  return *(const bf16x8*)&L[row * 256 + ((k16 ^ (row & 7)) << 3)];
}

// ---------------------------------------------------------------- L1: local tok (per-patch) + weight prep rider
DEVFN void trc_tile(const float* __restrict__ in, u16* __restrict__ out,
                    int R, int C, int r0, int c0, float (*tile)[33], int tid) {
  int tx = tid & 31, ty = tid >> 5;
  for (int i = ty; i < 32; i += 8) tile[i][tx] = in[(size_t)(r0 + i) * C + c0 + tx];
  __syncthreads();
  for (int i = ty; i < 32; i += 8)
    out[(size_t)(c0 + i) * R + r0 + tx] = bf16_rne(tile[tx][i]);
}

// blocks [0,216): block per (b,patch); reads the 2x2x2 patch ONCE (float2
// pairs), computes all 8 sub-position tokens + LN1 via one 17-sum reduction.
// g_part[b*27+patch] = exact raw-x partial (no overcount; divisor 55296).
// blocks [216,1496): weight prep.
__global__ __launch_bounds__(256) void k_l_tok_prep(
    const float* __restrict__ x, const float* __restrict__ pw,
    const float* __restrict__ pb, const float* __restrict__ g1,
    const float* __restrict__ b1, float* __restrict__ res,
    u16* __restrict__ eln_bf, float* __restrict__ g_part,
    const float* __restrict__ wq, const float* __restrict__ wk,
    const float* __restrict__ wv, const float* __restrict__ wo,
    const float* __restrict__ mow, u16* __restrict__ WcatT,
    u16* __restrict__ woT, u16* __restrict__ moB) {
  __shared__ __align__(16) char smem[8448];
  int bid0 = blockIdx.x, tid = threadIdx.x;
  if (bid0 < 216) {
    float* pws = (float*)smem;                       // 64
    float (*s17)[4] = (float(*)[4])(smem + 256);     // 17x4
    int b = bid0 / 27, patch = bid0 % 27;
    int pz = patch / 9, py = (patch / 3) % 3, px = patch % 3;
    int c = tid;
    if (c < 64) pws[c] = pw[c];
    __syncthreads();
    const float* xb = x + (size_t)(b * 256 + c) * 216 + (2 * pz) * 36 + (2 * py) * 6 + 2 * px;
    float2 t00 = *(const float2*)&xb[0],  t01 = *(const float2*)&xb[6];
    float2 t10 = *(const float2*)&xb[36], t11 = *(const float2*)&xb[42];
    float xv[8] = {t00.x, t00.y, t01.x, t01.y, t10.x, t10.y, t11.x, t11.y};
    float v[8];
    #pragma unroll
    for (int p = 0; p < 8; ++p) {
      float a = pb[p];
      #pragma unroll
      for (int j = 0; j < 8; ++j) a = fmaf(xv[j], pws[p * 8 + j], a);
      v[p] = a;
    }
    float sums[17];
    sums[0] = xv[0] + xv[1] + xv[2] + xv[3] + xv[4] + xv[5] + xv[6] + xv[7];
    #pragma unroll
    for (int p = 0; p < 8; ++p) { sums[1 + p] = v[p]; sums[9 + p] = v[p] * v[p]; }
    blk_sum17(sums, s17);
    if (c == 0) g_part[bid0] = sums[0];
    float gg = g1[c], bb = b1[c];
    #pragma unroll
    for (int p = 0; p < 8; ++p) {
      int sz = 2 * pz + (p >> 2), sy = 2 * py + ((p >> 1) & 1), sx = 2 * px + (p & 1);
      int t = b * 216 + sz * 36 + sy * 6 + sx;
      float mu = sums[1 + p] * (1.f / 256.f);
      float var = sums[9 + p] * (1.f / 256.f) - mu * mu;
      res[t * 256 + c] = v[p];
      eln_bf[t * 256 + c] = bf16_rne((v[p] - mu) * rsqrtf(var + 1e-6f) * gg + bb);
    }
  } else {
    float (*tile)[33] = (float(*)[33])smem;
    int bid = bid0 - 216;
    if (bid < 768) {            // wq/wk/wv: [256][1024] -> [1024][256]
      int which = bid >> 8, b2 = bid & 255;
      const float* in = (which == 0) ? wq : (which == 1) ? wk : wv;
      u16* out = WcatT + which * 262144;
      int r0 = (b2 & 7) * 32, c0 = (b2 >> 3) * 32;
      trc_tile(in, out, 256, 1024, r0, c0, tile, tid);
    } else if (bid < 1024) {    // wo: [1024][256] -> [256][1024]
      int b2 = bid - 768;
      int r0 = (b2 & 31) * 32, c0 = (b2 >> 5) * 32;
      trc_tile(wo, woT, 1024, 256, r0, c0, tile, tid);
    } else {                    // mo_w cast
      int i = (bid - 1024) * 256 + tid;
      moB[i] = bf16_rne(mow[i]);
    }
  }
}

// ---------------------------------------------------------------- L2: global qkv rider FIRST + local qkv GEMM
__global__ __launch_bounds__(256) void k_gemm_qkv_fused(
    const u16* __restrict__ A, const u16* __restrict__ BT, u16* __restrict__ C,
    const float* __restrict__ g_part, const float* __restrict__ tw_,
    const float* __restrict__ tb_, const float* __restrict__ g1,
    const float* __restrict__ b1, const float* __restrict__ wq,
    const float* __restrict__ wk, const float* __restrict__ wv,
    float* __restrict__ gqkv) {
  __shared__ __align__(16) char smem[65536];
  int bid = blockIdx.x, tid = threadIdx.x;
  if (bid < 48) {                 // ---- rider: runs concurrent with GEMM
    float* ts = (float*)smem;
    float (*red)[4][8] = (float(*)[4][8])(smem + 8192);
    float* s4 = (float*)(smem + 16384);
    float* m_s = (float*)(smem + 16400);
    float tw = tw_[tid], tb = tb_[tid], gg = g1[tid], bb = b1[tid];
    float S1 = blk_sum(tw, s4);
    float S2 = blk_sum(tw * tw, s4);
    float S3 = blk_sum(tb, s4);
    float S4 = blk_sum(tb * tb, s4);
    float S5 = blk_sum(tw * tb, s4);
    {
      int b = tid >> 5, sl = tid & 31;
      float a = (sl < 27) ? g_part[b * 27 + sl] : 0.f;
      #pragma unroll
      for (int o = 16; o > 0; o >>= 1) a += __shfl_down(a, o, 32);
      if (sl == 0) m_s[b] = a * (1.f / 55296.f);    // exact per-patch partials
    }
    __syncthreads();
    #pragma unroll
    for (int b = 0; b < 8; ++b) {
      float m = m_s[b];
      float mu = (m * S1 + S3) * (1.f / 256.f);
      float var = (m * m * S2 + 2.f * m * S5 + S4) * (1.f / 256.f) - mu * mu;
      ts[b * 256 + tid] = (m * tw + tb - mu) * rsqrtf(var + 1e-6f) * gg + bb;
    }
    __syncthreads();
    int col0 = bid * 64;
    int cl = tid & 63, kq = tid >> 6;
    int col = col0 + cl;
    int m = col >> 10, cc = col & 1023;
    const float* W = (m == 0) ? wq : (m == 1) ? wk : wv;
    float acc[8] = {};
    for (int c0 = kq * 64; c0 < kq * 64 + 64; c0 += 8) {
      float wbuf[8];
      #pragma unroll
      for (int j = 0; j < 8; ++j) wbuf[j] = W[(c0 + j) * 1024 + cc];  // 8 in flight
      #pragma unroll
      for (int j = 0; j < 8; ++j) {
        float w = wbuf[j];
        #pragma unroll
        for (int b = 0; b < 8; ++b) acc[b] = fmaf(ts[b * 256 + c0 + j], w, acc[b]);
      }
    }
    #pragma unroll
    for (int b = 0; b < 8; ++b) red[cl][kq][b] = acc[b];
    __syncthreads();
    if (kq == 0) {
      #pragma unroll
      for (int b = 0; b < 8; ++b)
        gqkv[b * 3072 + col] = red[cl][0][b] + red[cl][1][b] + red[cl][2][b] + red[cl][3][b];
    }
  } else {
    const int N = 3072, K = 256;
    u16* aL = (u16*)smem;          // chunk-major [32][64 rows][16B]
    u16* bL = (u16*)smem + 16384;
    int t0 = bid - 48;
    int tile = (t0 & 7) * 162 + (t0 >> 3);   // bijective XCD swizzle (1296=8*162)
    int rowblk = (tile % 27) * 64, colblk = (tile / 27) * 64;
    int lane = tid & 63, w = tid >> 6;
    int wr = (w >> 1) * 32, wc = (w & 1) * 32;
    int fm = lane & 15, lg = lane >> 4;
    #pragma unroll
    for (int i = 0; i < 8; ++i) {
      int c16 = w * 8 + i;                   // uniform chunk per instruction
      gload16(&A[(size_t)(rowblk + lane) * K + c16 * 8], aL + c16 * 512);
      gload16(&BT[(size_t)(colblk + lane) * K + c16 * 8], bL + c16 * 512);
    }
    __syncthreads();                         // single drain of all 16 loads
    f32x4 acc[2][2] = {};
    #pragma unroll
    for (int kk = 0; kk < 8; ++kk) {
      int k16 = kk * 4 + lg;
      bf16x8 bn0 = *(const bf16x8*)&bL[k16 * 512 + (wc + fm) * 8];
      bf16x8 bn1 = *(const bf16x8*)&bL[k16 * 512 + (wc + 16 + fm) * 8];
      bf16x8 af0 = *(const bf16x8*)&aL[k16 * 512 + (wr + fm) * 8];
      bf16x8 af1 = *(const bf16x8*)&aL[k16 * 512 + (wr + 16 + fm) * 8];
      acc[0][0] = __builtin_amdgcn_mfma_f32_16x16x32_bf16(af0, bn0, acc[0][0], 0, 0, 0);
      acc[0][1] = __builtin_amdgcn_mfma_f32_16x16x32_bf16(af0, bn1, acc[0][1], 0, 0, 0);
      acc[1][0] = __builtin_amdgcn_mfma_f32_16x16x32_bf16(af1, bn0, acc[1][0], 0, 0, 0);
      acc[1][1] = __builtin_amdgcn_mfma_f32_16x16x32_bf16(af1, bn1, acc[1][1], 0, 0, 0);
    }
    __syncthreads();                         // LDS safe to repurpose
    u16* ct = aL;                            // [64][72] bf16 (padded rows)
    #pragma unroll
    for (int mi = 0; mi < 2; ++mi)
      #pragma unroll
      for (int ni = 0; ni < 2; ++ni)
        #pragma unroll
        for (int r = 0; r < 4; ++r)
          ct[(wr + mi * 16 + lg * 4 + r) * 72 + wc + ni * 16 + fm] = bf16_rne(acc[mi][ni][r]);
    __syncthreads();
    #pragma unroll
    for (int pass = 0; pass < 2; ++pass) {
      int id = pass * 256 + tid;
      int r = id >> 3, u = id & 7;
      *(uint4*)&C[(size_t)(rowblk + r) * N + colblk + u * 8] = *(uint4*)&ct[r * 72 + u * 8];
    }
  }
}

// ---------------------------------------------------------------- L3: global attn rider FIRST + local attention
__global__ __launch_bounds__(256) void k_l_attn_fused(
    const u16* __restrict__ qkv, u16* __restrict__ o_buf,
    const float* __restrict__ gq, float* __restrict__ g_o) {
  __shared__ __align__(16) uint4 Qb[256], Kb[256];
  __shared__ __align__(16) u16 vt[16][264];
  __shared__ __align__(16) u16 Pl[256][72];
  __shared__ float rqA[64][4], rkA[64][4], rlq[64][4], rlk[64][4], s_ab[2];
  int bid = blockIdx.x, tid = threadIdx.x;
  if (bid < 32) {                         // ---- global attn rider (first)
    float* ks = (float*)Qb;               // overlay: 1KB
    float* vs = ks + 256;
    float* s4 = (float*)Kb;
    int b = bid >> 2, h = bid & 3;
    int i = tid;
    const float* base = gq + b * 3072 + h * 256;
    float q = base[i];
    float k = base[1024 + i];
    ks[i] = k;
    vs[i] = base[2048 + i];
    float sq  = blk_sum(q, s4);
    float sq2 = blk_sum(q * q, s4);
    float sk  = blk_sum(k, s4);
    float sk2 = blk_sum(k * k, s4);
    float tot  = sq * sk * (1.f / 65536.f);
    float tot2 = sq2 * sk2 * (1.f / 65536.f);
    float rstd = rsqrtf(tot2 - tot * tot + 1e-5f);
    float A = rstd, B = -tot * rstd;
    float den = 0.f, num = 0.f;
    for (int j = 0; j < 256; ++j) {
      float w = __expf(fmaf(q * ks[j], A, B));
      den += w; num += w * vs[j];
    }
    g_o[b * 1024 + (i << 2) + h] = num / den;
    return;
  }
  int nb = bid - 32;
  int n = nb >> 2, h = nb & 3;
  int b = n / 27, patch = n % 27;
  int bz = 2 * (patch / 9), by = 2 * ((patch / 3) % 3), bx = 2 * (patch % 3);
  {
    int c = tid;
    u16 qv[8], kv[8], vv[8];
    #pragma unroll
    for (int p = 0; p < 8; ++p) {
      int t_l = b * 216 + (bz + (p >> 2)) * 36 + (by + ((p >> 1) & 1)) * 6 + (bx + (p & 1));
      const u16* row = qkv + (size_t)t_l * 3072 + (c << 2) + h;
      qv[p] = row[0]; kv[p] = row[1024]; vv[p] = row[2048];
    }
    uint32_t qw[4], kw[4];
    #pragma unroll
    for (int i = 0; i < 4; ++i) {
      qw[i] = (uint32_t)qv[2 * i] | ((uint32_t)qv[2 * i + 1] << 16);
      kw[i] = (uint32_t)kv[2 * i] | ((uint32_t)kv[2 * i + 1] << 16);
    }
    Qb[c] = make_uint4(qw[0], qw[1], qw[2], qw[3]);
    Kb[c] = make_uint4(kw[0], kw[1], kw[2], kw[3]);
    #pragma unroll
    for (int p = 0; p < 8; ++p) vt[p][c] = vv[p];
    vt[8][c] = 0x3F80u;                  // bf16(1.0): denominator ones-row
    #pragma unroll
    for (int r2 = 9; r2 < 16; ++r2) vt[r2][c] = 0;
  }
  __syncthreads();
  {
    int p = tid & 63, chunk = tid >> 6;
    int d = p >> 3, e = p & 7;
    float aq = 0.f, ak = 0.f, lq = 0.f, lk = 0.f;
    for (int cc = chunk * 64; cc < chunk * 64 + 64; ++cc) {
      const u16* qr = (const u16*)&Qb[cc];
      const u16* kr = (const u16*)&Kb[cc];
      float qd = bf2f(qr[d]), qe = bf2f(qr[e]);
      float kd = bf2f(kr[d]), ke = bf2f(kr[e]);
      aq = fmaf(qd, qe, aq); ak = fmaf(kd, ke, ak);
      if (e == 0) { lq += qd; lk += kd; }
    }
    rqA[p][chunk] = aq; rkA[p][chunk] = ak; rlq[p][chunk] = lq; rlk[p][chunk] = lk;
    __syncthreads();
    if (tid < 64) {
      float gq2 = rqA[tid][0] + rqA[tid][1] + rqA[tid][2] + rqA[tid][3];
      float gk = rkA[tid][0] + rkA[tid][1] + rkA[tid][2] + rkA[tid][3];
      float vprod = gq2 * gk, vmu = 0.f;
      if ((tid & 7) == 0) {
        float slq = rlq[tid][0] + rlq[tid][1] + rlq[tid][2] + rlq[tid][3];
        float slk = rlk[tid][0] + rlk[tid][1] + rlk[tid][2] + rlk[tid][3];
        vmu = slq * slk;
      }
      #pragma unroll
      for (int o = 32; o > 0; o >>= 1) {
        vprod += __shfl_down(vprod, o, 64);
        vmu   += __shfl_down(vmu, o, 64);
      }
      if (tid == 0) {
        float mu = vmu * (1.f / 65536.f), m2 = vprod * (1.f / 65536.f);
        float rstd = rsqrtf(m2 - mu * mu + 1e-5f);
        s_ab[0] = rstd; s_ab[1] = -mu * rstd;
      }
    }
    __syncthreads();
  }
  float Af = s_ab[0], Bf = s_ab[1];
  int lane = tid & 63, w = tid >> 6;
  int l15 = lane & 15, lg = lane >> 4;
  bf16x8 qf[4];
  #pragma unroll
  for (int qt = 0; qt < 4; ++qt)
    qf[qt] = *(const bf16x8*)&Qb[w * 64 + qt * 16 + l15];
  f32x4 acc_o[4] = {};
  #pragma unroll 1
  for (int jc = 0; jc < 4; ++jc) {
    bf16x8 kf[4];
    #pragma unroll
    for (int jt = 0; jt < 4; ++jt) {
      bf16x8 z = {};
      if (lg == 0) z = *(const bf16x8*)&Kb[jc * 64 + jt * 16 + l15];
      kf[jt] = z;
    }
    #pragma unroll
    for (int jt = 0; jt < 4; ++jt) {
      #pragma unroll
      for (int qt = 0; qt < 4; ++qt) {
        f32x4 zc = {};
        f32x4 s = __builtin_amdgcn_mfma_f32_16x16x32_bf16(kf[jt], qf[qt], zc, 0, 0, 0);
        float e0 = __expf(fmaf(s[0], Af, Bf));
        float e1 = __expf(fmaf(s[1], Af, Bf));
        float e2 = __expf(fmaf(s[2], Af, Bf));
        float e3 = __expf(fmaf(s[3], Af, Bf));
        uint32_t w0 = (__float_as_uint(e0) >> 16) | (__float_as_uint(e1) & 0xFFFF0000u);
        uint32_t w1 = (__float_as_uint(e2) >> 16) | (__float_as_uint(e3) & 0xFFFF0000u);
        int q = w * 64 + qt * 16 + l15;
        *(uint2*)&Pl[q][jt * 16 + lg * 4] = make_uint2(w0, w1);
      }
    }
    #pragma unroll
    for (int ks2 = 0; ks2 < 2; ++ks2) {
      bf16x8 vf = *(const bf16x8*)&vt[l15][jc * 64 + ks2 * 32 + lg * 8];
      #pragma unroll
      for (int qt = 0; qt < 4; ++qt) {
        bf16x8 pf = *(const bf16x8*)&Pl[w * 64 + qt * 16 + l15][ks2 * 32 + lg * 8];
        acc_o[qt] = __builtin_amdgcn_mfma_f32_16x16x32_bf16(pf, vf, acc_o[qt], 0, 0, 0);
      }
    }
  }
  int src = ((lane & 48) + 8) << 2;
  int p = l15;
  int t_l = b * 216 + (bz + (p >> 2)) * 36 + (by + ((p >> 1) & 1)) * 6 + (bx + (p & 1));
  #pragma unroll
  for (int qt = 0; qt < 4; ++qt) {
    #pragma unroll
    for (int r = 0; r < 4; ++r) {
      float den = __int_as_float(__builtin_amdgcn_ds_bpermute(src, __float_as_int(acc_o[qt][r])));
      if (p < 8) {
        int q = w * 64 + qt * 16 + lg * 4 + r;
        o_buf[(size_t)t_l * 1024 + (q << 2) + h] = bf16_rne(acc_o[qt][r] / den);
      }
    }
  }
}

// ---------------------------------------------------------------- L4: global wo rider FIRST + split-K wo GEMM
__global__ __launch_bounds__(256) void k_gemm_sk_fused(
    const u16* __restrict__ A, const u16* __restrict__ BT, float* __restrict__ Cp,
    const float* __restrict__ g_o, const float* __restrict__ wo,
    float* __restrict__ part) {
  __shared__ __align__(16) char smem[65536];
  int bid = blockIdx.x, tid = threadIdx.x;
  if (bid < 32) {                           // ---- rider first
    float* os = (float*)smem;               // 8 x 32
    int kc = bid;
    os[tid] = g_o[(tid >> 5) * 1024 + kc * 32 + (tid & 31)];
    __syncthreads();
    float acc[8] = {};
    #pragma unroll
    for (int kk = 0; kk < 32; ++kk) {
      float w = wo[(size_t)(kc * 32 + kk) * 256 + tid];
      #pragma unroll
      for (int b = 0; b < 8; ++b) acc[b] = fmaf(os[b * 32 + kk], w, acc[b]);
    }
    #pragma unroll
    for (int b = 0; b < 8; ++b) part[kc * 2048 + b * 256 + tid] = acc[b];
  } else {
    const int M = 1728, N = 256, K = 1024;
    u16* aL = (u16*)smem;
    u16* bL = (u16*)smem + 16384;
    int bid2 = bid - 32;
    int rowblk = (bid2 % 27) * 64, colblk = ((bid2 / 27) & 3) * 64;
    int kz = bid2 / 108;
    float* C = Cp + (size_t)kz * M * N;
    int lane = tid & 63, w = tid >> 6;
    int wr = (w >> 1) * 32, wc = (w & 1) * 32;
    int fm = lane & 15, lg = lane >> 4;
    f32x4 acc[2][2] = {};
    #pragma unroll 1
    for (int step = 0; step < 2; ++step) {
      int kt = kz * 512 + step * 256;
      __syncthreads();
      stage64x256(A + (size_t)rowblk * K + kt, K, aL, w, lane);
      stage64x256(BT + (size_t)colblk * K + kt, K, bL, w, lane);
      __syncthreads();
      #pragma unroll
      for (int kk = 0; kk < 8; ++kk) {
        int k16 = kk * 4 + lg;
        bf16x8 bn0 = lread(bL, wc + fm, k16);
        bf16x8 bn1 = lread(bL, wc + 16 + fm, k16);
        bf16x8 af0 = lread(aL, wr + fm, k16);
        bf16x8 af1 = lread(aL, wr + 16 + fm, k16);
        acc[0][0] = __builtin_amdgcn_mfma_f32_16x16x32_bf16(af0, bn0, acc[0][0], 0, 0, 0);
        acc[0][1] = __builtin_amdgcn_mfma_f32_16x16x32_bf16(af0, bn1, acc[0][1], 0, 0, 0);
        acc[1][0] = __builtin_amdgcn_mfma_f32_16x16x32_bf16(af1, bn0, acc[1][0], 0, 0, 0);
        acc[1][1] = __builtin_amdgcn_mfma_f32_16x16x32_bf16(af1, bn1, acc[1][1], 0, 0, 0);
      }
    }
    __syncthreads();
    float* ct = (float*)smem;       // [64][64] fp32 C-tile (16KB)
    #pragma unroll
    for (int mi = 0; mi < 2; ++mi)
      #pragma unroll
      for (int ni = 0; ni < 2; ++ni)
        #pragma unroll
        for (int r = 0; r < 4; ++r)
          ct[(wr + mi * 16 + lg * 4 + r) * 64 + wc + ni * 16 + fm] = acc[mi][ni][r];
    __syncthreads();
    #pragma unroll
    for (int pass = 0; pass < 4; ++pass) {
      int id = pass * 256 + tid;
      int r = id >> 4, u = id & 15;
      *(float4*)&C[(size_t)(rowblk + r) * N + colblk + u * 4] = *(float4*)&ct[r * 64 + u * 4];
    }
  }
}

// ---------------------------------------------------------------- L5: global LN2 rider FIRST + local LN2
__global__ __launch_bounds__(256) void k_l_ln2_fused(
    const float* __restrict__ proj0, const float* __restrict__ proj1,
    const float* __restrict__ res, const float* __restrict__ g2,
    const float* __restrict__ b2, u16* __restrict__ t2b,
    const float* __restrict__ part, const float* __restrict__ g_part,
    const float* __restrict__ tw_, const float* __restrict__ tb_,
    const float* __restrict__ gg2, const float* __restrict__ gb2,
    float* __restrict__ t2g) {
  __shared__ float s2v[2][4];
  int bid = blockIdx.x, c = threadIdx.x;
  if (bid < 8) {
    int b = bid;
    float a = (c < 27) ? g_part[b * 27 + c] : 0.f;
    float m = blk_sum(a, (float*)s2v) * (1.f / 55296.f);
    float v = m * tw_[c] + tb_[c];
    #pragma unroll
    for (int kc = 0; kc < 32; ++kc) v += part[kc * 2048 + b * 256 + c];
    float r2[2];
    blk_sum2(v, v * v, r2, s2v);
    float mu = r2[0] * (1.f / 256.f);
    float var = r2[1] * (1.f / 256.f) - mu * mu;
    t2g[b * 256 + c] = (v - mu) * rsqrtf(var + 1e-6f) * gg2[c] + gb2[c];
  } else {
    int t = bid - 8;
    float v = proj0[t * 256 + c] + proj1[t * 256 + c] + res[t * 256 + c];
    float r2[2];
    blk_sum2(v, v * v, r2, s2v);
    float mu = r2[0] * (1.f / 256.f);
    float var = r2[1] * (1.f / 256.f) - mu * mu;
    t2b[t * 256 + c] = bf16_rne((v - mu) * rsqrtf(var + 1e-6f) * g2[c] + b2[c]);
  }
}

// ---------------------------------------------------------------- L6: global mo (standalone)
__global__ __launch_bounds__(256) void k_g_mo(
    const float* __restrict__ t2g, const float* __restrict__ mow,
    const float* __restrict__ mob, float* __restrict__ g_vec) {
  __shared__ float ts[2048];
  int tid = threadIdx.x;
  for (int i = tid; i < 2048; i += 256) ts[i] = t2g[i];
  __syncthreads();
  int ol = tid >> 5, cs = tid & 31;
  int o = blockIdx.x * 8 + ol;
  const float* wrow = mow + (size_t)o * 256;
  float acc[8] = {};
  #pragma unroll
  for (int i = 0; i < 8; ++i) {
    float w = wrow[i * 32 + cs];
    #pragma unroll
    for (int b = 0; b < 8; ++b) acc[b] = fmaf(ts[b * 256 + i * 32 + cs], w, acc[b]);
  }
  #pragma unroll
  for (int b = 0; b < 8; ++b) {
    float v = acc[b];
    #pragma unroll
    for (int off = 16; off > 0; off >>= 1) v += __shfl_down(v, off, 32);
    if (cs == 0) g_vec[b * 256 + o] = gelu_f(v + mob[o]);
  }
}

// ---------------------------------------------------------------- L7: mo GEMM + fused final
__global__ __launch_bounds__(256) void k_gemm_mo_final(
    const u16* __restrict__ A, const u16* __restrict__ BT,
    const float* __restrict__ x, const float* __restrict__ gvec,
    const float* __restrict__ mob, float* __restrict__ out) {
  __shared__ __align__(16) char smem[65536];
  u16* aL = (u16*)smem;
  u16* bL = (u16*)smem + 16384;
  float (*ct)[65] = (float(*)[65])smem;       // reused after k-loop
  const int K = 256;
  int tid = threadIdx.x;
  int rowblk = blockIdx.x * 64, colblk = blockIdx.y * 64;
  int lane = tid & 63, w = tid >> 6;
  int wr = (w >> 1) * 32, wc = (w & 1) * 32;
  int fm = lane & 15, lg = lane >> 4;
  stage64x256(A + (size_t)rowblk * K, K, aL, w, lane);
  stage64x256(BT + (size_t)colblk * K, K, bL, w, lane);
  __syncthreads();
  f32x4 acc[2][2] = {};
  #pragma unroll
  for (int kk = 0; kk < 8; ++kk) {
    int k16 = kk * 4 + lg;
    bf16x8 bn0 = lread(bL, wc + fm, k16);
    bf16x8 bn1 = lread(bL, wc + 16 + fm, k16);
    bf16x8 af0 = lread(aL, wr + fm, k16);
    bf16x8 af1 = lread(aL, wr + 16 + fm, k16);
    acc[0][0] = __builtin_amdgcn_mfma_f32_16x16x32_bf16(af0, bn0, acc[0][0], 0, 0, 0);
    acc[0][1] = __builtin_amdgcn_mfma_f32_16x16x32_bf16(af0, bn1, acc[0][1], 0, 0, 0);
    acc[1][0] = __builtin_amdgcn_mfma_f32_16x16x32_bf16(af1, bn0, acc[1][0], 0, 0, 0);
    acc[1][1] = __builtin_amdgcn_mfma_f32_16x16x32_bf16(af1, bn1, acc[1][1], 0, 0, 0);
  }
  __syncthreads();                            // LDS safe to repurpose
  int row_l0 = wr + lg * 4;
  #pragma unroll
  for (int mi = 0; mi < 2; ++mi)
    #pragma unroll
    for (int ni = 0; ni < 2; ++ni)
      #pragma unroll
      for (int r = 0; r < 4; ++r)
        ct[row_l0 + mi * 16 + r][wc + ni * 16 + fm] = acc[mi][ni][r];
  __syncthreads();
  int s_l = tid & 63;
  #pragma unroll 4
  for (int pass = 0; pass < 16; ++pass) {
    int col_l = (tid >> 6) * 16 + pass;
    int row = rowblk + s_l, col = colblk + col_l;
    int b = row / 216, s = row - b * 216;
    size_t idx = (size_t)b * 55296 + (size_t)col * 216 + s;
    out[idx] = x[idx] + gvec[b * 256 + col] + gelu_f(ct[s_l][col_l] + mob[col]);
  }
}

// ---------------------------------------------------------------- launcher
extern "C" void kernel_launch(void* const* d_in, const int* in_sizes, int n_in,
                              void* d_out, int out_size, void* d_ws, size_t ws_size,
                              hipStream_t stream) {
  const float* x     = (const float*)d_in[0];
  const float* g_tw  = (const float*)d_in[1];
  const float* g_tb  = (const float*)d_in[2];
  const float* g_l1g = (const float*)d_in[3];
  const float* g_l1b = (const float*)d_in[4];
  const float* g_wq  = (const float*)d_in[5];
  const float* g_wk  = (const float*)d_in[6];
  const float* g_wv  = (const float*)d_in[7];
  const float* g_wo  = (const float*)d_in[8];
  const float* g_l2g = (const float*)d_in[9];
  const float* g_l2b = (const float*)d_in[10];
  const float* g_mow = (const float*)d_in[11];
  const float* g_mob = (const float*)d_in[12];
  const float* l_pw  = (const float*)d_in[13];
  const float* l_pb  = (const float*)d_in[14];
  const float* l_l1g = (const float*)d_in[15];
  const float* l_l1b = (const float*)d_in[16];
  const float* l_wq  = (const float*)d_in[17];
  const float* l_wk  = (const float*)d_in[18];
  const float* l_wv  = (const float*)d_in[19];
  const float* l_wo  = (const float*)d_in[20];
  const float* l_l2g = (const float*)d_in[21];
  const float* l_l2b = (const float*)d_in[22];
  const float* l_mow = (const float*)d_in[23];
  const float* l_mob = (const float*)d_in[24];
  float* out = (float*)d_out;
  float* ws  = (float*)d_ws;

  // workspace layout (float offsets; bf16 regions hold 2 vals per float slot)
  float* g_qkv  = ws + 4096;     // 24576
  float* g_o    = ws + 28672;    // 8192
  float* g_vec  = ws + 36864;    // 2048
  float* g_part = ws + 38912;    // 216 (exact per-(b,patch) raw-x partials)
  float* res    = ws + 40960;    // 442368 f32
  u16*   eln_bf = (u16*)(ws + 483328);   // 442368 u16
  u16*   WcatT  = (u16*)(ws + 704512);   // 786432 u16 [3072 j][256 c]
  u16*   woT    = (u16*)(ws + 1097728);  // 262144 u16 [256][1024]
  u16*   moB    = (u16*)(ws + 1228800);  // 65536  u16
  u16*   qkvb   = (u16*)(ws + 1261568);  // 5308416 u16 (bf16 qkv)
  u16*   o_buf  = (u16*)(ws + 6569984);  // 1769472 u16
  float* proj   = ws + 7454720;  // 2 x 442368 f32 (split-K partials)
  u16*   t2b    = (u16*)(ws + 8339456);  // 442368 u16
  float* part_wo= ws + 8560640;  // 65536 (32 kc x 8 b x 256 c)
  float* t2g    = ws + 8626176;  // 2048

  // L1: local tok (per-patch, x read once) + weight prep rider
  k_l_tok_prep<<<1496, 256, 0, stream>>>(x, l_pw, l_pb, l_l1g, l_l1b,
                                         res, eln_bf, g_part,
                                         l_wq, l_wk, l_wv, l_wo, l_mow,
                                         WcatT, woT, moB);
  // L2: global qkv rider (blocks 0-47, concurrent) + local qkv GEMM
  k_gemm_qkv_fused<<<1344, 256, 0, stream>>>(eln_bf, WcatT, qkvb,
                                             g_part, g_tw, g_tb, g_l1g, g_l1b,
                                             g_wq, g_wk, g_wv, g_qkv);
  // L3: global attn rider (blocks 0-31) + local attention
  k_l_attn_fused<<<896, 256, 0, stream>>>(qkvb, o_buf, g_qkv, g_o);
  // L4: global wo rider (blocks 0-31) + split-K wo GEMM
  k_gemm_sk_fused<<<248, 256, 0, stream>>>(o_buf, woT, proj, g_o, g_wo, part_wo);
  // L5: global LN2 rider (blocks 0-7) + local LN2
  k_l_ln2_fused<<<1736, 256, 0, stream>>>(proj, proj + 442368, res,
                                          l_l2g, l_l2b, t2b,
                                          part_wo, g_part, g_tw, g_tb,
                                          g_l2g, g_l2b, t2g);
  // L6: global mo
  k_g_mo<<<32, 256, 0, stream>>>(t2g, g_mow, g_mob, g_vec);
  // L7: mo GEMM + fused final (coalesced epilogue)
  k_gemm_mo_final<<<dim3(27, 4), 256, 0, stream>>>(t2b, moB, x, g_vec, l_mob, out);
}